// Round 9
// baseline (638.244 us; speedup 1.0000x reference)
//
#include <hip/hip_runtime.h>
#include <hip/hip_cooperative_groups.h>
#include <stdint.h>

namespace cg = cooperative_groups;

// CrossAttention, linear-attention algebra, halves merged to M=16384.
// R16: algebraic fusion attn+o-proj (Wfin_b folds Wq,S_b,Wo).
// R18: ONE cooperative mega-kernel. Accounting showed ~145us of the 310us
// total is NOT inside any kernel: 10 serial dependent launches x ~10-14us
// dispatch+drain overhead (documented in harness notes). All stages become
// phases of a single 256-block x 512-thread cooperative kernel separated by
// grid.sync() (~1-2us each). Proven inner loops kept verbatim as __device__
// functions; LN rewritten wave-per-row (same math, no LDS); s_kernel/gemm_fuse
// run 2 virtual blocks per real block (identical barrier trip counts).
// Phases: 0 convert | 1 KV gemm256 | 2 S partials | 3 U(+c) | 4 Wfin |
//         5 o-proj(+res) | 6 LN1 | 7 FFN1 (2 tiles/block) | 8 FFN2 | 9 LN2.

#define Lq 2048
#define Dq 512
#define PFq 2048
#define Mrows 16384
#define MiBu 1048576ull
#define NSLICE 16

typedef __attribute__((ext_vector_type(8))) short frag_ab;
typedef __attribute__((ext_vector_type(4))) float frag_cd;
typedef __attribute__((ext_vector_type(8))) unsigned short ushort8v;

__device__ __forceinline__ unsigned short f2b(float f) {
    union { float f; uint32_t u; } x; x.f = f;
    uint32_t r = x.u + 0x7fffu + ((x.u >> 16) & 1u);
    return (unsigned short)(r >> 16);
}
__device__ __forceinline__ float b2f(unsigned short u) {
    union { uint32_t u; float f; } x; x.u = ((uint32_t)u) << 16;
    return x.f;
}

#define GLD16(g, l)                                                              \
    __builtin_amdgcn_global_load_lds(                                            \
        (const __attribute__((address_space(1))) void*)(const void*)(g),         \
        (__attribute__((address_space(3))) void*)(void*)(l), 16, 0, 0)

#define STG(BUFOFS, REGOFS, GB, ROWOFS, TILE, KS)                                \
    { GLD16((GB) + (size_t)(ROWOFS) * (KS) + (size_t)(TILE) * 64,                \
            Sh + (BUFOFS) + (REGOFS) + ld);                                      \
      GLD16((GB) + ((size_t)(ROWOFS) + 64) * (KS) + (size_t)(TILE) * 64,         \
            Sh + (BUFOFS) + (REGOFS) + ld + 4096); }

#define VMW(N) asm volatile("s_waitcnt vmcnt(" #N ")" ::: "memory")

#define PHASE(CB, M0, LOADB, STAGE_STMT, WAIT_STMT)                              \
    {                                                                            \
        frag_ab a00 = *(const frag_ab*)&Sh[(CB) + (wm + (M0)*16 + lr) * 64 + xo0];      \
        frag_ab a01 = *(const frag_ab*)&Sh[(CB) + (wm + (M0)*16 + lr) * 64 + xo1];      \
        frag_ab a10 = *(const frag_ab*)&Sh[(CB) + (wm + (M0)*16 + 16 + lr) * 64 + xo0]; \
        frag_ab a11 = *(const frag_ab*)&Sh[(CB) + (wm + (M0)*16 + 16 + lr) * 64 + xo1]; \
        if (LOADB) {                                                             \
            _Pragma("unroll")                                                    \
            for (int j = 0; j < 4; ++j) {                                        \
                bf[j][0] = *(const frag_ab*)&Sh[(CB) + 16384 + (wn + j*16 + lr)*64 + xo0]; \
                bf[j][1] = *(const frag_ab*)&Sh[(CB) + 16384 + (wn + j*16 + lr)*64 + xo1]; \
            }                                                                    \
        }                                                                        \
        STAGE_STMT;                                                              \
        WAIT_STMT;                                                               \
        __builtin_amdgcn_sched_barrier(0);                                       \
        __builtin_amdgcn_s_barrier();                                            \
        asm volatile("s_waitcnt lgkmcnt(0)" ::: "memory");                       \
        __builtin_amdgcn_sched_barrier(0);                                       \
        __builtin_amdgcn_s_setprio(1);                                           \
        _Pragma("unroll")                                                        \
        for (int j = 0; j < 4; ++j) {                                            \
            acc[(M0)][j]   = __builtin_amdgcn_mfma_f32_16x16x32_bf16(a00, bf[j][0], acc[(M0)][j], 0,0,0);   \
            acc[(M0)][j]   = __builtin_amdgcn_mfma_f32_16x16x32_bf16(a01, bf[j][1], acc[(M0)][j], 0,0,0);   \
            acc[(M0)+1][j] = __builtin_amdgcn_mfma_f32_16x16x32_bf16(a10, bf[j][0], acc[(M0)+1][j], 0,0,0); \
            acc[(M0)+1][j] = __builtin_amdgcn_mfma_f32_16x16x32_bf16(a11, bf[j][1], acc[(M0)+1][j], 0,0,0); \
        }                                                                        \
        __builtin_amdgcn_s_setprio(0);                                           \
        __builtin_amdgcn_sched_barrier(0);                                       \
        __builtin_amdgcn_s_barrier();                                            \
        __builtin_amdgcn_sched_barrier(0);                                       \
    }

// ---------------- 256x256 8-phase bf16 GEMM body (K=512) ---------------------
__device__ __forceinline__ void dev_gemm256(
    const unsigned short* __restrict__ A, const unsigned short* __restrict__ Wt,
    const float* __restrict__ bias, unsigned short* __restrict__ outB,
    int M, int N, int relu, int b0, unsigned short* Sh)
{
    const int tid = threadIdx.x;
    const int lane = tid & 63;
    const int w = tid >> 6;
    const int wm = (w >> 2) * 128;
    const int wn = (w & 3) * 64;
    const int lr = lane & 15;
    const int quad = lane >> 4;
    const int xo0 = ((quad ^ (lr & 7)) << 3);
    const int xo1 = (((4 | quad) ^ (lr & 7)) << 3);

    const int xcd = b0 & 7, slot = b0 >> 3;
    const int mloc = (M >> 8) >> 3;
    const size_t bm = (size_t)(xcd * mloc + slot % mloc) * 256;
    const size_t bn = (size_t)(slot / mloc) * 256;

    const int ar = tid >> 3;
    const int sw = ((tid & 7) ^ (ar & 7)) << 3;
    const unsigned short* Ag = A  + (bm + ar) * (size_t)512 + sw;
    const unsigned short* Bg = Wt + (bn + ar) * (size_t)512 + sw;
    const int ld = tid * 8;

    frag_cd acc[8][4] = {};
    frag_ab bf[4][2];

    STG(0,     16384, Bg, 0,   0, 512);
    STG(0,     24576, Bg, 128, 0, 512);
    STG(0,     0,     Ag, 0,   0, 512);
    STG(0,     8192,  Ag, 128, 0, 512);
    STG(32768, 16384, Bg, 0,   1, 512);
    STG(32768, 24576, Bg, 128, 1, 512);
    VMW(4);
    __builtin_amdgcn_sched_barrier(0);
    __builtin_amdgcn_s_barrier();
    __builtin_amdgcn_sched_barrier(0);

    for (int I = 0; I < 3; ++I) {
        const int tb = 2 * I + 1, tc = 2 * I + 2, td = 2 * I + 3;
        PHASE(0,     0, 1, STG(32768, 0,     Ag, 0,   tb, 512), (void)0);
        PHASE(0,     2, 0, STG(32768, 8192,  Ag, 128, tb, 512), (void)0);
        PHASE(0,     4, 0, STG(0,     16384, Bg, 0,   tc, 512), (void)0);
        PHASE(0,     6, 0, STG(0,     24576, Bg, 128, tc, 512), VMW(4));
        PHASE(32768, 0, 1, STG(0,     0,     Ag, 0,   tc, 512), (void)0);
        PHASE(32768, 2, 0, STG(0,     8192,  Ag, 128, tc, 512), (void)0);
        PHASE(32768, 4, 0, STG(32768, 16384, Bg, 0,   td, 512), (void)0);
        PHASE(32768, 6, 0, STG(32768, 24576, Bg, 128, td, 512), VMW(4));
    }
    PHASE(0,     0, 1, STG(32768, 0,    Ag, 0,   7, 512), (void)0);
    PHASE(0,     2, 0, STG(32768, 8192, Ag, 128, 7, 512), (void)0);
    PHASE(0,     4, 0, (void)0, (void)0);
    PHASE(0,     6, 0, (void)0, VMW(0));
    PHASE(32768, 0, 1, (void)0, (void)0);
    PHASE(32768, 2, 0, (void)0, (void)0);
    PHASE(32768, 4, 0, (void)0, (void)0);
    PHASE(32768, 6, 0, (void)0, (void)0);

    float bv[4];
#pragma unroll
    for (int j = 0; j < 4; ++j) bv[j] = bias[(int)bn + wn + j * 16 + lr];
    unsigned short* Cs = Sh + w * 8192;
#pragma unroll
    for (int m = 0; m < 8; ++m)
#pragma unroll
        for (int j = 0; j < 4; ++j)
#pragma unroll
            for (int r = 0; r < 4; ++r) {
                float v = acc[m][j][r] + bv[j];
                if (relu) v = fmaxf(v, 0.f);
                Cs[(m * 16 + quad * 4 + r) * 64 + j * 16 + lr] = f2b(v);
            }
    const int rl = lane >> 3, c8 = (lane & 7) * 8;
#pragma unroll
    for (int k = 0; k < 16; ++k) {
        const int row = rl + k * 8;
        ushort8v val = *(const ushort8v*)&Cs[row * 64 + c8];
        *(ushort8v*)(outB + (size_t)(bm + wm + row) * N + bn + wn + c8) = val;
    }
}

// ---------------- 256x128 4-phase GEMM body, runtime N/K ---------------------
// mode 0 plain; 2 in-place bf16 residual; 3 bf16 residual from res16.
__device__ __forceinline__ void dev_gemmn128(
    const unsigned short* __restrict__ A, const unsigned short* __restrict__ Wt,
    const float* __restrict__ bias, const unsigned short* __restrict__ res16,
    unsigned short* __restrict__ outB, int N, int K, int mode, int perb,
    int b0, unsigned short* Sh)
{
    const int tid = threadIdx.x;
    const int lane = tid & 63;
    const int w = tid >> 6;
    const int wm = (w >> 1) * 64;
    const int wn = (w & 1) * 64;
    const int lr = lane & 15;
    const int quad = lane >> 4;
    const int xo0 = ((quad ^ (lr & 7)) << 3);
    const int xo1 = (((4 | quad) ^ (lr & 7)) << 3);

    const int xcd = b0 & 7, slot = b0 >> 3;
    const size_t bm = (size_t)(xcd * 8 + (slot & 7)) * 256;
    const size_t bn = (size_t)(slot >> 3) * 128;

    if (perb) {
        const int bsel = ((int)(bm >> 11)) & 3;
        Wt += (size_t)bsel << 18;
        bias += bsel << 9;
    }

    const int ar = tid >> 3;
    const int sw = ((tid & 7) ^ (ar & 7)) << 3;
    const unsigned short* Ag = A  + (bm + ar) * (size_t)K + sw;
    const unsigned short* Bg = Wt + (bn + ar) * (size_t)K + sw;
    const int ld = tid * 8;

    frag_cd acc[4][4] = {};
    frag_ab bf[4][2];

    STG(0,     16384, Bg, 0,   0, K);
    STG(0,     0,     Ag, 0,   0, K);
    STG(0,     8192,  Ag, 128, 0, K);
    STG(24576, 16384, Bg, 0,   1, K);
    VMW(2);
    __builtin_amdgcn_sched_barrier(0);
    __builtin_amdgcn_s_barrier();
    __builtin_amdgcn_sched_barrier(0);

    const int nIter = K >> 7;
    for (int I = 0; I < nIter - 1; ++I) {
        const int tb = 2 * I + 1, tc = 2 * I + 2, td = 2 * I + 3;
        PHASE(0,     0, 1, { STG(24576, 0, Ag, 0, tb, K); STG(24576, 8192, Ag, 128, tb, K); }, (void)0);
        PHASE(0,     2, 0, STG(0, 16384, Bg, 0, tc, K), VMW(2));
        PHASE(24576, 0, 1, { STG(0, 0, Ag, 0, tc, K); STG(0, 8192, Ag, 128, tc, K); }, (void)0);
        PHASE(24576, 2, 0, STG(24576, 16384, Bg, 0, td, K), VMW(2));
    }
    {
        const int tb = (K >> 6) - 1;
        PHASE(0,     0, 1, { STG(24576, 0, Ag, 0, tb, K); STG(24576, 8192, Ag, 128, tb, K); }, (void)0);
        PHASE(0,     2, 0, (void)0, VMW(0));
        PHASE(24576, 0, 1, (void)0, (void)0);
        PHASE(24576, 2, 0, (void)0, (void)0);
    }

    float bv[4];
#pragma unroll
    for (int j = 0; j < 4; ++j) bv[j] = bias[(int)bn + wn + j * 16 + lr];
    unsigned short* Cs = Sh + w * 4096;
#pragma unroll
    for (int m = 0; m < 4; ++m)
#pragma unroll
        for (int j = 0; j < 4; ++j)
#pragma unroll
            for (int r = 0; r < 4; ++r)
                Cs[(m * 16 + quad * 4 + r) * 64 + j * 16 + lr] = f2b(acc[m][j][r] + bv[j]);
    const int rl = lane >> 3, c8 = (lane & 7) * 8;
#pragma unroll
    for (int k = 0; k < 8; ++k) {
        const int row = rl + k * 8;
        const int grow = (int)bm + wm + row;
        const size_t idx = (size_t)grow * N + bn + wn + c8;
        ushort8v val = *(const ushort8v*)&Cs[row * 64 + c8];
        if (mode == 0) {
            *(ushort8v*)(outB + idx) = val;
            continue;
        }
        float vv[8];
#pragma unroll
        for (int t2 = 0; t2 < 8; ++t2) vv[t2] = b2f(val[t2]);
        {
            const unsigned short* rp16 = (mode == 2) ? (outB + idx) : (res16 + idx);
            ushort8v old = *(const ushort8v*)rp16;
#pragma unroll
            for (int t2 = 0; t2 < 8; ++t2) vv[t2] += b2f(old[t2]);
        }
        ushort8v o;
#pragma unroll
        for (int t2 = 0; t2 < 8; ++t2) o[t2] = f2b(vv[t2]);
        *(ushort8v*)(outB + idx) = o;
    }
}

// ---------------- S partials body (256-thread virtual block) -----------------
__device__ __forceinline__ void dev_s(
    const unsigned short* __restrict__ QKV, float* __restrict__ Spart,
    int vb, int t, float* Ks, float* Vs)
{
    const int bh = vb >> 4;              // 0..31
    const int sl = vb & 15;              // 0..15
    const int b = bh >> 3, h = bh & 7;
    const int pass = sl >> 3;
    const int l0 = (sl & 7) * 256;
    const int tx = t & 15, ty = t >> 4;
    const int srow = t >> 3;
    const int scol = (t & 7) * 8;
    const size_t rowbase = (size_t)pass * 8192 + (size_t)b * Lq + l0;

    float acc[4][4] = {};

    for (int t0 = 0; t0 < 256; t0 += 64) {
        const unsigned short* kp0 = QKV + (rowbase + t0 + srow) * 1024 + h * 64 + scol;
        const unsigned short* kp1 = kp0 + (size_t)32 * 1024;
        ushort8v k0 = *(const ushort8v*)kp0;
        ushort8v v0 = *(const ushort8v*)(kp0 + 512);
        ushort8v k1 = *(const ushort8v*)kp1;
        ushort8v v1 = *(const ushort8v*)(kp1 + 512);
        __syncthreads();
#pragma unroll
        for (int e = 0; e < 8; ++e) {
            Ks[srow * 64 + scol + e]        = b2f(k0[e]);
            Vs[srow * 64 + scol + e]        = b2f(v0[e]);
            Ks[(srow + 32) * 64 + scol + e] = b2f(k1[e]);
            Vs[(srow + 32) * 64 + scol + e] = b2f(v1[e]);
        }
        __syncthreads();
#pragma unroll 4
        for (int rr = 0; rr < 64; ++rr) {
            const float4 kf = *(const float4*)&Ks[rr * 64 + ty * 4];
            const float4 vf = *(const float4*)&Vs[rr * 64 + tx * 4];
            acc[0][0] = fmaf(kf.x, vf.x, acc[0][0]);
            acc[0][1] = fmaf(kf.x, vf.y, acc[0][1]);
            acc[0][2] = fmaf(kf.x, vf.z, acc[0][2]);
            acc[0][3] = fmaf(kf.x, vf.w, acc[0][3]);
            acc[1][0] = fmaf(kf.y, vf.x, acc[1][0]);
            acc[1][1] = fmaf(kf.y, vf.y, acc[1][1]);
            acc[1][2] = fmaf(kf.y, vf.z, acc[1][2]);
            acc[1][3] = fmaf(kf.y, vf.w, acc[1][3]);
            acc[2][0] = fmaf(kf.z, vf.x, acc[2][0]);
            acc[2][1] = fmaf(kf.z, vf.y, acc[2][1]);
            acc[2][2] = fmaf(kf.z, vf.z, acc[2][2]);
            acc[2][3] = fmaf(kf.z, vf.w, acc[2][3]);
            acc[3][0] = fmaf(kf.w, vf.x, acc[3][0]);
            acc[3][1] = fmaf(kf.w, vf.y, acc[3][1]);
            acc[3][2] = fmaf(kf.w, vf.z, acc[3][2]);
            acc[3][3] = fmaf(kf.w, vf.w, acc[3][3]);
        }
    }

    float* Sp = Spart + ((size_t)bh * NSLICE + sl) * 4096;
#pragma unroll
    for (int i = 0; i < 4; ++i) {
        float4 o = make_float4(acc[i][0], acc[i][1], acc[i][2], acc[i][3]);
        *(float4*)(Sp + (ty * 4 + i) * 64 + tx * 4) = o;
    }
}

// ---------------- U (+c) body: 512 threads, blocks 0..63 ---------------------
__device__ __forceinline__ void dev_u(
    const float* __restrict__ Spart, const unsigned short* __restrict__ Wqb,
    const unsigned short* __restrict__ Wob, const float* __restrict__ bq,
    unsigned short* __restrict__ UT, float* __restrict__ biasO,
    int bh, int jh, float* Sf, float* rsh)
{
    const int b = bh >> 3, h = bh & 7;
    const int t = threadIdx.x;
    const float* Sp = Spart + (size_t)bh * (NSLICE * 4096);
#pragma unroll
    for (int e = 0; e < 8; ++e) {
        const int d = e * 512 + t;
        float v = 0.f;
#pragma unroll
        for (int s = 0; s < NSLICE; ++s) v += Sp[(size_t)s * 4096 + d];
        Sf[d] = v;
    }
    __syncthreads();

    const int j0 = jh * 32;
    float T[32] = {};
    for (int k = 0; k < 64; ++k) {
        const float wq = b2f(Wqb[(h * 64 + k) * 512 + t]);
#pragma unroll
        for (int j = 0; j < 32; ++j)
            T[j] = fmaf(wq, Sf[k * 64 + j0 + j], T[j]);
    }
    unsigned short* up = UT + ((size_t)(b * 512 + t)) * 512 + h * 64 + j0;
#pragma unroll
    for (int g = 0; g < 4; ++g) {
        ushort8v o;
#pragma unroll
        for (int e = 0; e < 8; ++e) o[e] = f2b(T[g * 8 + e]);
        *(ushort8v*)(up + g * 8) = o;
    }

    if (t < 32) {
        float r = 0.f;
        for (int k = 0; k < 64; ++k) r += bq[h * 64 + k] * Sf[k * 64 + j0 + t];
        rsh[t] = r;
    }
    __syncthreads();
    float c = 0.f;
#pragma unroll
    for (int j = 0; j < 32; ++j)
        c += rsh[j] * b2f(Wob[(size_t)t * 512 + h * 64 + j0 + j]);
    atomicAdd(&biasO[b * 512 + t], c);
}

// ------- Wfin = Wo @ U, 128x128 tile, 256-thread virtual block ---------------
__device__ __forceinline__ void dev_fuse(
    const unsigned short* __restrict__ Wob, const unsigned short* __restrict__ UT,
    unsigned short* __restrict__ Wfin, int vb, int t, unsigned short* Sh)
{
    unsigned short* At = Sh;
    unsigned short* Bt = Sh + 128 * 64;
    const int lane = t & 63;
    const int w = t >> 6;                // 0..3
    const int wm = (w >> 1) * 64, wn = (w & 1) * 64;
    const int lr = lane & 15;
    const int quad = lane >> 4;
    const int bb = vb >> 4;
    const size_t bm = (size_t)(vb & 3) * 128, bn = (size_t)((vb >> 2) & 3) * 128;

    frag_cd acc[4][4] = {};
    const int ar = t >> 3;
    const int acs = (((t & 7) ^ (ar & 7)) << 3);
    const unsigned short* Ag = Wob + (bm + ar) * 512 + acs;
    const unsigned short* Bg = UT + ((size_t)bb << 18) + (bn + ar) * 512 + acs;
    unsigned short* Asd = At + w * 512;
    unsigned short* Bsd = Bt + w * 512;

    for (int k0 = 0; k0 < 512; k0 += 64) {
        __syncthreads();
#pragma unroll
        for (int i = 0; i < 4; ++i) {
            GLD16(Ag + (size_t)(32 * i) * 512 + k0, Asd + i * 2048);
            GLD16(Bg + (size_t)(32 * i) * 512 + k0, Bsd + i * 2048);
        }
        __syncthreads();
#pragma unroll
        for (int kk = 0; kk < 2; ++kk) {
            frag_ab a[4], b[4];
#pragma unroll
            for (int i = 0; i < 4; ++i)
                a[i] = *(const frag_ab*)&At[(wm + i * 16 + lr) * 64 +
                                            ((((kk << 2) | quad) ^ (lr & 7)) << 3)];
#pragma unroll
            for (int j = 0; j < 4; ++j)
                b[j] = *(const frag_ab*)&Bt[(wn + j * 16 + lr) * 64 +
                                            ((((kk << 2) | quad) ^ (lr & 7)) << 3)];
#pragma unroll
            for (int i = 0; i < 4; ++i)
#pragma unroll
                for (int j = 0; j < 4; ++j)
                    acc[i][j] = __builtin_amdgcn_mfma_f32_16x16x32_bf16(a[i], b[j], acc[i][j], 0, 0, 0);
        }
    }
    __syncthreads();
    unsigned short* Cs = Sh + w * 4096;
#pragma unroll
    for (int j = 0; j < 4; ++j)
#pragma unroll
        for (int i = 0; i < 4; ++i)
#pragma unroll
            for (int r = 0; r < 4; ++r)
                Cs[(i * 16 + quad * 4 + r) * 64 + j * 16 + lr] = f2b(acc[i][j][r]);
    const int rl = lane >> 3, c8 = (lane & 7) * 8;
#pragma unroll
    for (int k = 0; k < 8; ++k) {
        const int row = rl + k * 8;
        ushort8v val = *(const ushort8v*)&Cs[row * 64 + c8];
        *(ushort8v*)(Wfin + ((size_t)bb << 18) + (bm + wm + row) * 512 + bn + wn + c8) = val;
    }
}

// ------- LN wave-per-row: out==null -> bf16 in place; else f32 halves --------
__device__ __forceinline__ void dev_ln(
    unsigned short* __restrict__ Y, const float* __restrict__ g,
    const float* __restrict__ bta, float* __restrict__ out, int blk, int tid)
{
    const int wv = tid >> 6, lane = tid & 63;
    const int c0 = lane * 8;
    float4 ga = *(const float4*)(g + c0), gb = *(const float4*)(g + c0 + 4);
    float4 ba = *(const float4*)(bta + c0), bb = *(const float4*)(bta + c0 + 4);
    const float gv[8] = {ga.x, ga.y, ga.z, ga.w, gb.x, gb.y, gb.z, gb.w};
    const float bv[8] = {ba.x, ba.y, ba.z, ba.w, bb.x, bb.y, bb.z, bb.w};
#pragma unroll
    for (int r = 0; r < 8; ++r) {
        const int row = blk * 64 + r * 8 + wv;
        unsigned short* yr = Y + (size_t)row * Dq;
        ushort8v v = *(const ushort8v*)(yr + c0);
        float f[8];
        float s = 0.f;
#pragma unroll
        for (int e = 0; e < 8; ++e) { f[e] = b2f(v[e]); s += f[e]; }
#pragma unroll
        for (int off = 32; off; off >>= 1) s += __shfl_xor(s, off, 64);
        const float mean = s * (1.f / Dq);
        float q = 0.f;
#pragma unroll
        for (int e = 0; e < 8; ++e) { f[e] -= mean; q += f[e] * f[e]; }
#pragma unroll
        for (int off = 32; off; off >>= 1) q += __shfl_xor(q, off, 64);
        const float rstd = rsqrtf(q * (1.f / Dq) + 1e-5f);
        if (out) {
            const int half = row >> 13, br = row & 8191;
            float* orow = out + (size_t)br * 1024 + half * 512 + c0;
            float4 o0, o1;
            o0.x = f[0] * rstd * gv[0] + bv[0];
            o0.y = f[1] * rstd * gv[1] + bv[1];
            o0.z = f[2] * rstd * gv[2] + bv[2];
            o0.w = f[3] * rstd * gv[3] + bv[3];
            o1.x = f[4] * rstd * gv[4] + bv[4];
            o1.y = f[5] * rstd * gv[5] + bv[5];
            o1.z = f[6] * rstd * gv[6] + bv[6];
            o1.w = f[7] * rstd * gv[7] + bv[7];
            *(float4*)orow = o0;
            *(float4*)(orow + 4) = o1;
        } else {
            ushort8v o;
#pragma unroll
            for (int e = 0; e < 8; ++e) o[e] = f2b(f[e] * rstd * gv[e] + bv[e]);
            *(ushort8v*)(yr + c0) = o;
        }
    }
}

// =========================== THE MEGA-KERNEL =================================
__global__ __launch_bounds__(512, 2) void mega(
    const float* __restrict__ question, const float* __restrict__ query,
    const float* __restrict__ Wq, const float* __restrict__ bqp,
    const float* __restrict__ Wk, const float* __restrict__ bkp,
    const float* __restrict__ Wv, const float* __restrict__ bvp,
    const float* __restrict__ Wo, const float* __restrict__ bo,
    const float* __restrict__ ln_g, const float* __restrict__ ln_b,
    const float* __restrict__ W1, const float* __restrict__ b1,
    const float* __restrict__ W2, const float* __restrict__ b2,
    float* __restrict__ out,
    unsigned short* __restrict__ QKVb, unsigned short* __restrict__ UT,
    unsigned short* __restrict__ Wfin, float* __restrict__ Spart,
    unsigned short* __restrict__ Xb, unsigned short* __restrict__ xbuf,
    unsigned short* __restrict__ hb,
    unsigned short* __restrict__ Wqkvb, unsigned short* __restrict__ Wob,
    unsigned short* __restrict__ W1b, unsigned short* __restrict__ W2b,
    float* __restrict__ biasO, float* __restrict__ bqkv)
{
    __shared__ __align__(16) unsigned short Sh[65536];   // 128 KiB
    cg::grid_group grid = cg::this_grid();
    const int blk = blockIdx.x;
    const int tid = threadIdx.x;

    // ---- phase 0: converts + bias concat + biasO init (grid-strided) ----
    for (int vb = blk * 2 + (tid >> 8); vb < 11278; vb += 512) {
        const int t = tid & 255;
        const float* src; unsigned short* dst; size_t off;
        if (vb < 256)        { src = Wq; dst = Wqkvb;          off = (size_t)vb * 1024; }
        else if (vb < 512)   { src = Wk; dst = Wqkvb + 262144; off = (size_t)(vb - 256) * 1024; }
        else if (vb < 768)   { src = Wv; dst = Wqkvb + 524288; off = (size_t)(vb - 512) * 1024; }
        else if (vb < 1024)  { src = Wo; dst = Wob;            off = (size_t)(vb - 768) * 1024; }
        else if (vb < 2048)  { src = W1; dst = W1b;            off = (size_t)(vb - 1024) * 1024; }
        else if (vb < 3072)  { src = W2; dst = W2b;            off = (size_t)(vb - 2048) * 1024; }
        else if (vb < 7168)  { src = question; dst = Xb;       off = (size_t)(vb - 3072) * 1024; }
        else if (vb < 11264) { src = query; dst = Xb + 4194304; off = (size_t)(vb - 7168) * 1024; }
        else if (vb < 11270) {
            const int n = (vb - 11264) * 256 + t;
            bqkv[n] = (n < 512) ? bqp[n] : (n < 1024) ? bkp[n - 512] : bvp[n - 1024];
            continue;
        } else {
            const int n = (vb - 11270) * 256 + t;
            biasO[n] = bo[n & 511];
            continue;
        }
        const size_t idx = off + t * 4;
        float4 v = *(const float4*)(src + idx);
        ushort4 o;
        o.x = f2b(v.x); o.y = f2b(v.y); o.z = f2b(v.z); o.w = f2b(v.w);
        *(ushort4*)(dst + idx) = o;
    }
    grid.sync();

    // ---- phase 1: KV = X @ [Wk;Wv]^T + bias (256 blocks = 1 round) ----
    dev_gemm256(Xb, Wqkvb + 262144, bqkv + 512, QKVb, Mrows, 1024, 0, blk, Sh);
    grid.sync();

    // ---- phase 2: S partials (2 virtual blocks per block) ----
    {
        const int sub = tid >> 8, t = tid & 255;
        float* base = (float*)Sh + sub * 8192;           // 32 KB per sub-block
        dev_s(QKVb, Spart, blk * 2 + sub, t, base, base + 4096);
    }
    grid.sync();

    // ---- phase 3: U (+c) on blocks 0..63 ----
    if (blk < 64)
        dev_u(Spart, Wqkvb, Wob, bqkv, UT, biasO, blk >> 1, blk & 1,
              (float*)Sh, (float*)Sh + 4096);
    grid.sync();

    // ---- phase 4: Wfin = Wo @ U on blocks 0..31 (2 virtual each) ----
    if (blk < 32) {
        const int sub = tid >> 8, t = tid & 255;
        dev_fuse(Wob, UT, Wfin, blk * 2 + sub, t, Sh + sub * 16384);
    }
    grid.sync();

    // ---- phase 5: fused attn+o-proj: xbuf = X @ Wfin_b^T + biasO_b + Xb ----
    dev_gemmn128(Xb, Wfin, biasO, Xb, xbuf, 512, 512, 3, 1, blk, Sh);
    grid.sync();

    // ---- phase 6: LN1 in place ----
    dev_ln(xbuf, ln_g, ln_b, nullptr, blk, tid);
    grid.sync();

    // ---- phase 7: FFN1 = relu(xbuf @ W1^T + b1), 512 tiles = 2 per block ----
    dev_gemm256(xbuf, W1b, b1, hb, Mrows, PFq, 1, blk, Sh);
    __syncthreads();
    dev_gemm256(xbuf, W1b, b1, hb, Mrows, PFq, 1, blk + 256, Sh);
    grid.sync();

    // ---- phase 8: FFN2 = hb @ W2^T + b2 + xbuf (in place) ----
    dev_gemmn128(hb, W2b, b2, nullptr, xbuf, 512, 2048, 2, 0, blk, Sh);
    grid.sync();

    // ---- phase 9: LN2 -> out halves ----
    dev_ln(xbuf, ln_g, ln_b, out, blk, tid);
}

extern "C" void kernel_launch(void* const* d_in, const int* in_sizes, int n_in,
                              void* d_out, int out_size, void* d_ws, size_t ws_size,
                              hipStream_t stream)
{
    const float* question = (const float*)d_in[0];
    const float* query    = (const float*)d_in[1];
    const float* Wq = (const float*)d_in[2];  const float* bqp = (const float*)d_in[3];
    const float* Wk = (const float*)d_in[4];  const float* bkp = (const float*)d_in[5];
    const float* Wv = (const float*)d_in[6];  const float* bvp = (const float*)d_in[7];
    const float* Wo = (const float*)d_in[8];  const float* bo  = (const float*)d_in[9];
    const float* ln_g = (const float*)d_in[10]; const float* ln_b = (const float*)d_in[11];
    const float* W1 = (const float*)d_in[12]; const float* b1 = (const float*)d_in[13];
    const float* W2 = (const float*)d_in[14]; const float* b2 = (const float*)d_in[15];
    float* out = (float*)d_out;
    char* ws = (char*)d_ws;

    // ---- workspace (~86 MiB) ----
    unsigned short* QKVb = (unsigned short*)(ws);                // [16384][1024] 32 MiB
    unsigned short* UT   = (unsigned short*)(ws + 32 * MiBu);    // 2 MiB
    unsigned short* Wfin = (unsigned short*)(ws + 34 * MiBu);    // 2 MiB
    float* Spart         = (float*)(ws + 40 * MiBu);             // 8 MiB
    unsigned short* Xb   = (unsigned short*)(ws + 48 * MiBu);    // 16 MiB (dead before hb covers it)
    unsigned short* hb   = (unsigned short*)(ws);                // [16384][2048] 64 MiB (phase 7+)
    unsigned short* xbuf = (unsigned short*)(ws + 64 * MiBu);    // 16 MiB
    char* wp = ws + 80 * MiBu;
    unsigned short* Wqkvb = (unsigned short*)wp;  wp += 1536 * 512 * 2;
    unsigned short* Wob   = (unsigned short*)wp;  wp += 512 * 512 * 2;
    unsigned short* W1b   = (unsigned short*)wp;  wp += 2048 * 512 * 2;
    unsigned short* W2b   = (unsigned short*)wp;  wp += 512 * 2048 * 2;
    float* biasO          = (float*)wp;           wp += 4 * 512 * 4;
    float* bqkv           = (float*)wp;

    void* args[] = {
        (void*)&question, (void*)&query,
        (void*)&Wq, (void*)&bqp, (void*)&Wk, (void*)&bkp, (void*)&Wv, (void*)&bvp,
        (void*)&Wo, (void*)&bo, (void*)&ln_g, (void*)&ln_b,
        (void*)&W1, (void*)&b1, (void*)&W2, (void*)&b2,
        (void*)&out,
        (void*)&QKVb, (void*)&UT, (void*)&Wfin, (void*)&Spart,
        (void*)&Xb, (void*)&xbuf, (void*)&hb,
        (void*)&Wqkvb, (void*)&Wob, (void*)&W1b, (void*)&W2b,
        (void*)&biasO, (void*)&bqkv
    };
    hipLaunchCooperativeKernel((const void*)mega, dim3(256), dim3(512),
                               args, 0, stream);
}

// Round 10
// 307.828 us; speedup vs baseline: 2.0734x; 2.0734x over previous
//
#include <hip/hip_runtime.h>
#include <stdint.h>

// CrossAttention via linear-attention algebra, both halves merged to M=16384:
//   S = K1^T V1 + K2^T V2 (per b,h; 64x64), shared by both halves.
//   attn = Q @ S ; x = LN(inp + attn@Wo^T + bo) ; out = LN(x + FF(x))
// R19: REVERT to R14 (best measured, 301.0us). R15 triple-buffer (-FETCH reuse),
// R16/R17 algebraic fusion (serial small-kernel chain ate the savings), and
// R18 cooperative mega-kernel (grid.sync ~35-40us each on 8 XCDs: MfmaUtil 7%,
// +110MB FETCH / +125MB WRITE from per-sync L2 flush) all REGRESSED and are
// reverted. One addition vs R14: o-proj residual from bf16 Xb (mode 3; Xb
// parked in d_out, dead until final LN) instead of 64MB f32 question/query:
// -32MB epilogue FETCH, numerics margin verified in R17.

#define Bq 4
#define Lq 2048
#define Dq 512
#define PFq 2048
#define Mrows 16384
#define MiBu 1048576ull
#define NSLICE 16

typedef __attribute__((ext_vector_type(8))) short frag_ab;
typedef __attribute__((ext_vector_type(4))) float frag_cd;
typedef __attribute__((ext_vector_type(8))) unsigned short ushort8v;

__device__ __forceinline__ unsigned short f2b(float f) {
    union { float f; uint32_t u; } x; x.f = f;
    uint32_t r = x.u + 0x7fffu + ((x.u >> 16) & 1u);
    return (unsigned short)(r >> 16);
}
__device__ __forceinline__ float b2f(unsigned short u) {
    union { uint32_t u; float f; } x; x.u = ((uint32_t)u) << 16;
    return x.f;
}

#define GLD16(g, l)                                                              \
    __builtin_amdgcn_global_load_lds(                                            \
        (const __attribute__((address_space(1))) void*)(const void*)(g),         \
        (__attribute__((address_space(3))) void*)(void*)(l), 16, 0, 0)

// One stage unit: 128 rows x 64 k-cols bf16 (2x global_load_lds_dwordx4/thread)
#define STG(BUFOFS, REGOFS, GB, ROWOFS, TILE, KS)                                \
    { GLD16((GB) + (size_t)(ROWOFS) * (KS) + (size_t)(TILE) * 64,                \
            Sh + (BUFOFS) + (REGOFS) + ld);                                      \
      GLD16((GB) + ((size_t)(ROWOFS) + 64) * (KS) + (size_t)(TILE) * 64,         \
            Sh + (BUFOFS) + (REGOFS) + ld + 4096); }

#define VMW(N) asm volatile("s_waitcnt vmcnt(" #N ")" ::: "memory")

// One phase: ds-read 2 M-frags (+8 B-frags if LOADB), issue stages, counted
// wait, barrier, 16 MFMA under setprio, barrier.
#define PHASE(CB, M0, LOADB, STAGE_STMT, WAIT_STMT)                              \
    {                                                                            \
        frag_ab a00 = *(const frag_ab*)&Sh[(CB) + (wm + (M0)*16 + lr) * 64 + xo0];      \
        frag_ab a01 = *(const frag_ab*)&Sh[(CB) + (wm + (M0)*16 + lr) * 64 + xo1];      \
        frag_ab a10 = *(const frag_ab*)&Sh[(CB) + (wm + (M0)*16 + 16 + lr) * 64 + xo0]; \
        frag_ab a11 = *(const frag_ab*)&Sh[(CB) + (wm + (M0)*16 + 16 + lr) * 64 + xo1]; \
        if (LOADB) {                                                             \
            _Pragma("unroll")                                                    \
            for (int j = 0; j < 4; ++j) {                                        \
                bf[j][0] = *(const frag_ab*)&Sh[(CB) + 16384 + (wn + j*16 + lr)*64 + xo0]; \
                bf[j][1] = *(const frag_ab*)&Sh[(CB) + 16384 + (wn + j*16 + lr)*64 + xo1]; \
            }                                                                    \
        }                                                                        \
        STAGE_STMT;                                                              \
        WAIT_STMT;                                                               \
        __builtin_amdgcn_sched_barrier(0);                                       \
        __builtin_amdgcn_s_barrier();                                            \
        asm volatile("s_waitcnt lgkmcnt(0)" ::: "memory");                       \
        __builtin_amdgcn_sched_barrier(0);                                       \
        __builtin_amdgcn_s_setprio(1);                                           \
        _Pragma("unroll")                                                        \
        for (int j = 0; j < 4; ++j) {                                            \
            acc[(M0)][j]   = __builtin_amdgcn_mfma_f32_16x16x32_bf16(a00, bf[j][0], acc[(M0)][j], 0,0,0);   \
            acc[(M0)][j]   = __builtin_amdgcn_mfma_f32_16x16x32_bf16(a01, bf[j][1], acc[(M0)][j], 0,0,0);   \
            acc[(M0)+1][j] = __builtin_amdgcn_mfma_f32_16x16x32_bf16(a10, bf[j][0], acc[(M0)+1][j], 0,0,0); \
            acc[(M0)+1][j] = __builtin_amdgcn_mfma_f32_16x16x32_bf16(a11, bf[j][1], acc[(M0)+1][j], 0,0,0); \
        }                                                                        \
        __builtin_amdgcn_s_setprio(0);                                           \
        __builtin_amdgcn_sched_barrier(0);                                       \
        __builtin_amdgcn_s_barrier();                                            \
        __builtin_amdgcn_sched_barrier(0);                                       \
    }

// ================== 256x256 8-phase bf16 GEMM (K=512 fixed) ==================
__global__ __launch_bounds__(512, 2) void gemm_256(
    const unsigned short* __restrict__ A, const unsigned short* __restrict__ Wt,
    const float* __restrict__ bias, unsigned short* __restrict__ outB,
    int M, int N, int relu)
{
    __shared__ __align__(16) unsigned short Sh[65536];   // 128 KiB
    const int tid = threadIdx.x;
    const int lane = tid & 63;
    const int w = tid >> 6;              // 0..7
    const int wm = (w >> 2) * 128;       // 0 / 128
    const int wn = (w & 3) * 64;         // 0..192
    const int lr = lane & 15;
    const int quad = lane >> 4;
    const int xo0 = ((quad ^ (lr & 7)) << 3);
    const int xo1 = (((4 | quad) ^ (lr & 7)) << 3);

    // 2D XCD chunking
    const int b0 = blockIdx.x;
    const int xcd = b0 & 7, slot = b0 >> 3;
    const int mloc = (M >> 8) >> 3;
    const size_t bm = (size_t)(xcd * mloc + slot % mloc) * 256;
    const size_t bn = (size_t)(slot / mloc) * 256;

    const int ar = tid >> 3;
    const int sw = ((tid & 7) ^ (ar & 7)) << 3;
    const unsigned short* Ag = A  + (bm + ar) * (size_t)512 + sw;
    const unsigned short* Bg = Wt + (bn + ar) * (size_t)512 + sw;
    const int ld = tid * 8;

    frag_cd acc[8][4] = {};
    frag_ab bf[4][2];

    STG(0,     16384, Bg, 0,   0, 512);
    STG(0,     24576, Bg, 128, 0, 512);
    STG(0,     0,     Ag, 0,   0, 512);
    STG(0,     8192,  Ag, 128, 0, 512);
    STG(32768, 16384, Bg, 0,   1, 512);
    STG(32768, 24576, Bg, 128, 1, 512);
    VMW(4);
    __builtin_amdgcn_sched_barrier(0);
    __builtin_amdgcn_s_barrier();
    __builtin_amdgcn_sched_barrier(0);

    for (int I = 0; I < 3; ++I) {
        const int tb = 2 * I + 1, tc = 2 * I + 2, td = 2 * I + 3;
        PHASE(0,     0, 1, STG(32768, 0,     Ag, 0,   tb, 512), (void)0);
        PHASE(0,     2, 0, STG(32768, 8192,  Ag, 128, tb, 512), (void)0);
        PHASE(0,     4, 0, STG(0,     16384, Bg, 0,   tc, 512), (void)0);
        PHASE(0,     6, 0, STG(0,     24576, Bg, 128, tc, 512), VMW(4));
        PHASE(32768, 0, 1, STG(0,     0,     Ag, 0,   tc, 512), (void)0);
        PHASE(32768, 2, 0, STG(0,     8192,  Ag, 128, tc, 512), (void)0);
        PHASE(32768, 4, 0, STG(32768, 16384, Bg, 0,   td, 512), (void)0);
        PHASE(32768, 6, 0, STG(32768, 24576, Bg, 128, td, 512), VMW(4));
    }
    PHASE(0,     0, 1, STG(32768, 0,    Ag, 0,   7, 512), (void)0);
    PHASE(0,     2, 0, STG(32768, 8192, Ag, 128, 7, 512), (void)0);
    PHASE(0,     4, 0, (void)0, (void)0);
    PHASE(0,     6, 0, (void)0, VMW(0));
    PHASE(32768, 0, 1, (void)0, (void)0);
    PHASE(32768, 2, 0, (void)0, (void)0);
    PHASE(32768, 4, 0, (void)0, (void)0);
    PHASE(32768, 6, 0, (void)0, (void)0);

    float bv[4];
#pragma unroll
    for (int j = 0; j < 4; ++j) bv[j] = bias[(int)bn + wn + j * 16 + lr];
    unsigned short* Cs = Sh + w * 8192;
#pragma unroll
    for (int m = 0; m < 8; ++m)
#pragma unroll
        for (int j = 0; j < 4; ++j)
#pragma unroll
            for (int r = 0; r < 4; ++r) {
                float v = acc[m][j][r] + bv[j];
                if (relu) v = fmaxf(v, 0.f);
                Cs[(m * 16 + quad * 4 + r) * 64 + j * 16 + lr] = f2b(v);
            }
    const int rl = lane >> 3, c8 = (lane & 7) * 8;
#pragma unroll
    for (int k = 0; k < 16; ++k) {
        const int row = rl + k * 8;
        ushort8v val = *(const ushort8v*)&Cs[row * 64 + c8];
        *(ushort8v*)(outB + (size_t)(bm + wm + row) * N + bn + wn + c8) = val;
    }
}

// ======= 256x128 4-phase GEMM, runtime N (out stride) and K ==================
// mode 0: outB = A@W^T + bias ; 1: + f32 residual resA/resB (rows <8192 /
// >=8192) ; 2: + b2f(outB) in place ; 3: + bf16 residual from res16.
__global__ __launch_bounds__(512, 2) void gemm_n128(
    const unsigned short* __restrict__ A, const unsigned short* __restrict__ Wt,
    const float* __restrict__ bias,
    const float* __restrict__ resA, const float* __restrict__ resB,
    const unsigned short* __restrict__ res16,
    unsigned short* __restrict__ outB, int N, int K, int mode)
{
    __shared__ __align__(16) unsigned short Sh[49152];   // 96 KiB
    const int tid = threadIdx.x;
    const int lane = tid & 63;
    const int w = tid >> 6;              // 0..7
    const int wm = (w >> 1) * 64;        // 0/64/128/192
    const int wn = (w & 1) * 64;         // 0/64
    const int lr = lane & 15;
    const int quad = lane >> 4;
    const int xo0 = ((quad ^ (lr & 7)) << 3);
    const int xo1 = (((4 | quad) ^ (lr & 7)) << 3);

    // 2D XCD chunking: xcd owns 8 consecutive m-tiles x all n-tiles.
    const int b0 = blockIdx.x;
    const int xcd = b0 & 7, slot = b0 >> 3;
    const size_t bm = (size_t)(xcd * 8 + (slot & 7)) * 256;
    const size_t bn = (size_t)(slot >> 3) * 128;

    const int ar = tid >> 3;
    const int sw = ((tid & 7) ^ (ar & 7)) << 3;
    const unsigned short* Ag = A  + (bm + ar) * (size_t)K + sw;
    const unsigned short* Bg = Wt + (bn + ar) * (size_t)K + sw;
    const int ld = tid * 8;

    frag_cd acc[4][4] = {};
    frag_ab bf[4][2];

    // prologue: aB aA0 aA1 bB ; wait all but bB
    STG(0,     16384, Bg, 0,   0, K);
    STG(0,     0,     Ag, 0,   0, K);
    STG(0,     8192,  Ag, 128, 0, K);
    STG(24576, 16384, Bg, 0,   1, K);
    VMW(2);
    __builtin_amdgcn_sched_barrier(0);
    __builtin_amdgcn_s_barrier();
    __builtin_amdgcn_sched_barrier(0);

    const int nIter = K >> 7;            // 2 K-tiles per iteration
    for (int I = 0; I < nIter - 1; ++I) {
        const int tb = 2 * I + 1, tc = 2 * I + 2, td = 2 * I + 3;
        PHASE(0,     0, 1, { STG(24576, 0, Ag, 0, tb, K); STG(24576, 8192, Ag, 128, tb, K); }, (void)0);
        PHASE(0,     2, 0, STG(0, 16384, Bg, 0, tc, K), VMW(2));
        PHASE(24576, 0, 1, { STG(0, 0, Ag, 0, tc, K); STG(0, 8192, Ag, 128, tc, K); }, (void)0);
        PHASE(24576, 2, 0, STG(24576, 16384, Bg, 0, td, K), VMW(2));
    }
    {   // tail
        const int tb = (K >> 6) - 1;
        PHASE(0,     0, 1, { STG(24576, 0, Ag, 0, tb, K); STG(24576, 8192, Ag, 128, tb, K); }, (void)0);
        PHASE(0,     2, 0, (void)0, VMW(0));
        PHASE(24576, 0, 1, (void)0, (void)0);
        PHASE(24576, 2, 0, (void)0, (void)0);
    }

    float bv[4];
#pragma unroll
    for (int j = 0; j < 4; ++j) bv[j] = bias[(int)bn + wn + j * 16 + lr];
    unsigned short* Cs = Sh + w * 4096;
#pragma unroll
    for (int m = 0; m < 4; ++m)
#pragma unroll
        for (int j = 0; j < 4; ++j)
#pragma unroll
            for (int r = 0; r < 4; ++r)
                Cs[(m * 16 + quad * 4 + r) * 64 + j * 16 + lr] = f2b(acc[m][j][r] + bv[j]);
    const int rl = lane >> 3, c8 = (lane & 7) * 8;
#pragma unroll
    for (int k = 0; k < 8; ++k) {
        const int row = rl + k * 8;
        const int grow = (int)bm + wm + row;
        const size_t idx = (size_t)grow * N + bn + wn + c8;
        ushort8v val = *(const ushort8v*)&Cs[row * 64 + c8];
        if (mode == 0) {
            *(ushort8v*)(outB + idx) = val;
            continue;
        }
        float vv[8];
#pragma unroll
        for (int t2 = 0; t2 < 8; ++t2) vv[t2] = b2f(val[t2]);
        if (mode == 1) {
            const float* rp = (grow < 8192) ? resA + idx : resB + idx - (size_t)8192 * N;
            float4 ra = *(const float4*)(rp);
            float4 rb = *(const float4*)(rp + 4);
            vv[0] += ra.x; vv[1] += ra.y; vv[2] += ra.z; vv[3] += ra.w;
            vv[4] += rb.x; vv[5] += rb.y; vv[6] += rb.z; vv[7] += rb.w;
        } else {
            const unsigned short* rp16 = (mode == 2) ? (outB + idx) : (res16 + idx);
            ushort8v old = *(const ushort8v*)rp16;
#pragma unroll
            for (int t2 = 0; t2 < 8; ++t2) vv[t2] += b2f(old[t2]);
        }
        ushort8v o;
#pragma unroll
        for (int t2 = 0; t2 < 8; ++t2) o[t2] = f2b(vv[t2]);
        *(ushort8v*)(outB + idx) = o;
    }
}

// -------- merged fp32->bf16 converts + QKV bias concat --------
__global__ __launch_bounds__(256) void convert_all(
    const float* __restrict__ Wq, const float* __restrict__ Wk,
    const float* __restrict__ Wv, const float* __restrict__ Wo,
    const float* __restrict__ W1, const float* __restrict__ W2,
    const float* __restrict__ question, const float* __restrict__ query,
    const float* __restrict__ bqp, const float* __restrict__ bkp,
    const float* __restrict__ bvp,
    unsigned short* __restrict__ Wqkvb, unsigned short* __restrict__ Wob,
    unsigned short* __restrict__ W1b, unsigned short* __restrict__ W2b,
    unsigned short* __restrict__ Xb, float* __restrict__ bqkv)
{
    const int b = blockIdx.x;
    const float* src; unsigned short* dst; size_t off;
    if (b < 256)        { src = Wq; dst = Wqkvb;          off = (size_t)b * 1024; }
    else if (b < 512)   { src = Wk; dst = Wqkvb + 262144; off = (size_t)(b - 256) * 1024; }
    else if (b < 768)   { src = Wv; dst = Wqkvb + 524288; off = (size_t)(b - 512) * 1024; }
    else if (b < 1024)  { src = Wo; dst = Wob;            off = (size_t)(b - 768) * 1024; }
    else if (b < 2048)  { src = W1; dst = W1b;            off = (size_t)(b - 1024) * 1024; }
    else if (b < 3072)  { src = W2; dst = W2b;            off = (size_t)(b - 2048) * 1024; }
    else if (b < 7168)  { src = question; dst = Xb;       off = (size_t)(b - 3072) * 1024; }
    else if (b < 11264) { src = query; dst = Xb + 4194304; off = (size_t)(b - 7168) * 1024; }
    else {
        const int n = (b - 11264) * 256 + threadIdx.x;   // 0..1535
        bqkv[n] = (n < 512) ? bqp[n] : (n < 1024) ? bkp[n - 512] : bvp[n - 1024];
        return;
    }
    const size_t idx = off + threadIdx.x * 4;
    float4 v = *(const float4*)(src + idx);
    ushort4 o;
    o.x = f2b(v.x); o.y = f2b(v.y); o.z = f2b(v.z); o.w = f2b(v.w);
    *(ushort4*)(dst + idx) = o;
}

// ------- Spart[bh][slice] = sum over 256 l-rows of K^T outer V (merged QKV) ----
__global__ __launch_bounds__(256) void s_kernel(
    const unsigned short* __restrict__ QKV, float* __restrict__ Spart)
{
    const int bh = blockIdx.x;           // 0..31
    const int sl = blockIdx.y;           // 0..NSLICE-1
    const int b = bh >> 3, h = bh & 7;
    const int pass = sl >> 3;
    const int l0 = (sl & 7) * 256;
    __shared__ float Ks[64][64];
    __shared__ float Vs[64][64];
    const int tid = threadIdx.x;
    const int tx = tid & 15, ty = tid >> 4;
    const int srow = tid >> 3;
    const int scol = (tid & 7) * 8;
    const size_t rowbase = (size_t)pass * 8192 + (size_t)b * Lq + l0;

    float acc[4][4] = {};

    for (int t0 = 0; t0 < 256; t0 += 64) {
        const unsigned short* kp0 = QKV + (rowbase + t0 + srow) * 1536 + 512 + h * 64 + scol;
        const unsigned short* kp1 = kp0 + (size_t)32 * 1536;
        ushort8v k0 = *(const ushort8v*)kp0;
        ushort8v v0 = *(const ushort8v*)(kp0 + 512);
        ushort8v k1 = *(const ushort8v*)kp1;
        ushort8v v1 = *(const ushort8v*)(kp1 + 512);
        __syncthreads();
#pragma unroll
        for (int e = 0; e < 8; ++e) {
            Ks[srow][scol + e]      = b2f(k0[e]);
            Vs[srow][scol + e]      = b2f(v0[e]);
            Ks[srow + 32][scol + e] = b2f(k1[e]);
            Vs[srow + 32][scol + e] = b2f(v1[e]);
        }
        __syncthreads();
#pragma unroll 4
        for (int rr = 0; rr < 64; ++rr) {
            const float4 kf = *(const float4*)&Ks[rr][ty * 4];
            const float4 vf = *(const float4*)&Vs[rr][tx * 4];
            acc[0][0] = fmaf(kf.x, vf.x, acc[0][0]);
            acc[0][1] = fmaf(kf.x, vf.y, acc[0][1]);
            acc[0][2] = fmaf(kf.x, vf.z, acc[0][2]);
            acc[0][3] = fmaf(kf.x, vf.w, acc[0][3]);
            acc[1][0] = fmaf(kf.y, vf.x, acc[1][0]);
            acc[1][1] = fmaf(kf.y, vf.y, acc[1][1]);
            acc[1][2] = fmaf(kf.y, vf.z, acc[1][2]);
            acc[1][3] = fmaf(kf.y, vf.w, acc[1][3]);
            acc[2][0] = fmaf(kf.z, vf.x, acc[2][0]);
            acc[2][1] = fmaf(kf.z, vf.y, acc[2][1]);
            acc[2][2] = fmaf(kf.z, vf.z, acc[2][2]);
            acc[2][3] = fmaf(kf.z, vf.w, acc[2][3]);
            acc[3][0] = fmaf(kf.w, vf.x, acc[3][0]);
            acc[3][1] = fmaf(kf.w, vf.y, acc[3][1]);
            acc[3][2] = fmaf(kf.w, vf.z, acc[3][2]);
            acc[3][3] = fmaf(kf.w, vf.w, acc[3][3]);
        }
    }

    float* Sp = Spart + ((size_t)bh * NSLICE + sl) * 4096;
#pragma unroll
    for (int i = 0; i < 4; ++i) {
        float4 o = make_float4(acc[i][0], acc[i][1], acc[i][2], acc[i][3]);
        *(float4*)(Sp + (ty * 4 + i) * 64 + tx * 4) = o;
    }
}

// ------- reduce NSLICE partials -> Sbt bf16, B-layout [bh][khalf][n][kj] -------
__global__ __launch_bounds__(256) void sbt_convert(
    const float* __restrict__ Spart, unsigned short* __restrict__ Sbt)
{
    const int bh = blockIdx.x;
    const int uo = blockIdx.y;           // 0..3
    const float* Sp = Spart + (size_t)bh * (NSLICE * 4096);
    unsigned short* Dp = Sbt + (size_t)bh * 4096;
    const int t = threadIdx.x;
#pragma unroll
    for (int u = 0; u < 4; ++u) {
        const int d = (uo * 4 + u) * 256 + t;
        float v = 0.f;
#pragma unroll
        for (int s = 0; s < NSLICE; ++s) v += Sp[(size_t)s * 4096 + d];
        const int row = d >> 6, col = d & 63;
        Dp[(row >> 5) * 2048 + col * 32 + (row & 31)] = f2b(v);
    }
}

// ------- attn = Q @ S_bh via MFMA; block: 128 rows x 64 cols (one head) -------
__global__ __launch_bounds__(256) void attn_mfma(
    const unsigned short* __restrict__ QKV, const unsigned short* __restrict__ Sbt,
    unsigned short* __restrict__ Ob)
{
    __shared__ __align__(16) unsigned short Sh[2 * 128 * 32 + 2 * 64 * 32];
    unsigned short* At = Sh;
    unsigned short* Bt = Sh + 2 * 128 * 32;
    const int h = blockIdx.x;
    const int rbase = blockIdx.y * 128;
    const int b = (rbase >> 11) & 3;
    const int bh = b * 8 + h;
    const int tid = threadIdx.x;
    const int lane = tid & 63;
    const int w = tid >> 6;
    const int lr = lane & 15;
    const int quad = lane >> 4;

    {
        const int rloc = tid >> 2, c8 = (tid & 3) * 8;
#pragma unroll
        for (int it = 0; it < 4; ++it) {
            const int kk = it & 1, rh = it >> 1;
            const unsigned short* g = QKV +
                ((size_t)rbase + rh * 64 + rloc) * 1536 + h * 64 + kk * 32 + c8;
            GLD16(g, At + kk * 4096 + rh * 2048 + w * 512);
        }
        const unsigned short* Sg = Sbt + (size_t)bh * 4096 + tid * 8;
#pragma unroll
        for (int bi = 0; bi < 2; ++bi)
            GLD16(Sg + bi * 2048, Bt + bi * 2048 + w * 512);
    }
    __syncthreads();

    frag_cd acc[2][4] = {};
#pragma unroll
    for (int kk = 0; kk < 2; ++kk) {
        frag_ab a[2], bfr[4];
#pragma unroll
        for (int i = 0; i < 2; ++i)
            a[i] = *(const frag_ab*)&At[kk * 4096 + (w * 32 + i * 16 + lr) * 32 + quad * 8];
#pragma unroll
        for (int j = 0; j < 4; ++j)
            bfr[j] = *(const frag_ab*)&Bt[kk * 2048 + (j * 16 + lr) * 32 + quad * 8];
#pragma unroll
        for (int i = 0; i < 2; ++i)
#pragma unroll
            for (int j = 0; j < 4; ++j)
                acc[i][j] = __builtin_amdgcn_mfma_f32_16x16x32_bf16(a[i], bfr[j], acc[i][j], 0, 0, 0);
    }

    __syncthreads();
    unsigned short* Cs = Sh + w * 2048;
#pragma unroll
    for (int i = 0; i < 2; ++i)
#pragma unroll
        for (int j = 0; j < 4; ++j)
#pragma unroll
            for (int r = 0; r < 4; ++r)
                Cs[(i * 16 + quad * 4 + r) * 64 + j * 16 + lr] = f2b(acc[i][j][r]);
    const int rl = lane >> 3;
    const int c8o = (lane & 7) * 8;
#pragma unroll
    for (int k = 0; k < 4; ++k) {
        const int row = rl + k * 8;
        ushort8v val = *(const ushort8v*)&Cs[row * 64 + c8o];
        *(ushort8v*)(Ob + (size_t)(rbase + w * 32 + row) * 512 + h * 64 + c8o) = val;
    }
}

// ------- LN over bf16 row (512) in place; wave-shuffle reduction -------
__global__ __launch_bounds__(256) void ln_b16_inplace(
    unsigned short* __restrict__ Y, const float* __restrict__ g,
    const float* __restrict__ bta)
{
    __shared__ float part[8];
    const int row = blockIdx.x;
    const int t = threadIdx.x;
    const int w = t >> 6;
    unsigned short* yr = Y + (size_t)row * Dq;
    const float v0 = b2f(yr[t]), v1 = b2f(yr[t + 256]);
    float s = v0 + v1;
#pragma unroll
    for (int off = 32; off; off >>= 1) s += __shfl_xor(s, off, 64);
    if ((t & 63) == 0) part[w] = s;
    __syncthreads();
    const float mean = (part[0] + part[1] + part[2] + part[3]) * (1.f / Dq);
    const float d0 = v0 - mean, d1 = v1 - mean;
    float q = d0 * d0 + d1 * d1;
#pragma unroll
    for (int off = 32; off; off >>= 1) q += __shfl_xor(q, off, 64);
    if ((t & 63) == 0) part[4 + w] = q;
    __syncthreads();
    const float rstd = rsqrtf((part[4] + part[5] + part[6] + part[7]) * (1.f / Dq) + 1e-5f);
    yr[t] = f2b(d0 * rstd * g[t] + bta[t]);
    yr[t + 256] = f2b(d1 * rstd * g[t + 256] + bta[t + 256]);
}

// ------- LN over bf16 row -> out f32 half-columns (merged rows) -------
__global__ __launch_bounds__(256) void ln_b16_out(
    const unsigned short* __restrict__ Y, const float* __restrict__ g,
    const float* __restrict__ bta, float* __restrict__ out)
{
    __shared__ float part[8];
    const int row = blockIdx.x;
    const int t = threadIdx.x;
    const int w = t >> 6;
    const unsigned short* yr = Y + (size_t)row * Dq;
    const float v0 = b2f(yr[t]), v1 = b2f(yr[t + 256]);
    float s = v0 + v1;
#pragma unroll
    for (int off = 32; off; off >>= 1) s += __shfl_xor(s, off, 64);
    if ((t & 63) == 0) part[w] = s;
    __syncthreads();
    const float mean = (part[0] + part[1] + part[2] + part[3]) * (1.f / Dq);
    const float d0 = v0 - mean, d1 = v1 - mean;
    float q = d0 * d0 + d1 * d1;
#pragma unroll
    for (int off = 32; off; off >>= 1) q += __shfl_xor(q, off, 64);
    if ((t & 63) == 0) part[4 + w] = q;
    __syncthreads();
    const float rstd = rsqrtf((part[4] + part[5] + part[6] + part[7]) * (1.f / Dq) + 1e-5f);
    const int half = row >> 13, br = row & 8191;
    float* orow = out + (size_t)br * 1024 + half * 512;
    orow[t] = d0 * rstd * g[t] + bta[t];
    orow[t + 256] = d1 * rstd * g[t + 256] + bta[t + 256];
}

extern "C" void kernel_launch(void* const* d_in, const int* in_sizes, int n_in,
                              void* d_out, int out_size, void* d_ws, size_t ws_size,
                              hipStream_t stream)
{
    const float* question = (const float*)d_in[0];
    const float* query    = (const float*)d_in[1];
    const float* Wq = (const float*)d_in[2];  const float* bqp = (const float*)d_in[3];
    const float* Wk = (const float*)d_in[4];  const float* bkp = (const float*)d_in[5];
    const float* Wv = (const float*)d_in[6];  const float* bvp = (const float*)d_in[7];
    const float* Wo = (const float*)d_in[8];  const float* bo  = (const float*)d_in[9];
    const float* ln_g = (const float*)d_in[10]; const float* ln_b = (const float*)d_in[11];
    const float* W1 = (const float*)d_in[12]; const float* b1 = (const float*)d_in[13];
    const float* W2 = (const float*)d_in[14]; const float* b2 = (const float*)d_in[15];
    float* out = (float*)d_out;
    char* ws = (char*)d_ws;

    // ---- workspace; Xb parked in d_out (dead before ln_b16_out overwrites) ----
    unsigned short* QKVb  = (unsigned short*)(ws);               // [16384][1536] 48 MiB
    unsigned short* attnb = (unsigned short*)(ws + 48 * MiBu);   // 16 MiB
    float* Spart          = (float*)(ws + 48 * MiBu);            // 8 MiB, dead before attnb
    unsigned short* xbuf  = (unsigned short*)(ws + 64 * MiBu);   // 16 MiB
    unsigned short* hb    = (unsigned short*)(ws);               // [16384][2048] 64 MiB
    unsigned short* Xb    = (unsigned short*)d_out;              // 16 MiB scratch
    char* wp = ws + 80 * MiBu + 524288;
    unsigned short* Wqkvb = (unsigned short*)wp;  wp += 1536 * 512 * 2;
    unsigned short* Wob   = (unsigned short*)wp;  wp += 512 * 512 * 2;
    unsigned short* W1b   = (unsigned short*)wp;  wp += 2048 * 512 * 2;
    unsigned short* W2b   = (unsigned short*)wp;  wp += 512 * 2048 * 2;
    unsigned short* Sbt   = (unsigned short*)wp;  wp += 32 * 4096 * 2;
    float* bqkv           = (float*)wp;

    dim3 blk(256);

    convert_all<<<11270, blk, 0, stream>>>(Wq, Wk, Wv, Wo, W1, W2, question, query,
                                           bqp, bkp, bvp,
                                           Wqkvb, Wob, W1b, W2b, Xb, bqkv);

    // QKV: [16384,512]@[1536,512]^T -> bf16 (256x128 4-phase; 768 blocks = 3 rounds)
    gemm_n128<<<dim3(768), dim3(512), 0, stream>>>(Xb, Wqkvb, bqkv,
                                                   nullptr, nullptr, nullptr, QKVb,
                                                   1536, 512, 0);

    // S partials (fp32, no atomics) -> reduce+pack bf16 B-layout; attn via MFMA
    s_kernel<<<dim3(32, NSLICE), blk, 0, stream>>>(QKVb, Spart);
    sbt_convert<<<dim3(32, 4), blk, 0, stream>>>(Spart, Sbt);
    attn_mfma<<<dim3(8, 128), blk, 0, stream>>>(QKVb, Sbt, attnb);

    // o-proj + bo + bf16 residual (Xb) -> bf16 y0b (256 blocks)
    gemm_n128<<<dim3(256), dim3(512), 0, stream>>>(attnb, Wob, bo,
                                                   nullptr, nullptr, Xb, xbuf,
                                                   512, 512, 3);

    // LN1 in place: xb = LN(y0b)
    ln_b16_inplace<<<Mrows, blk, 0, stream>>>(xbuf, ln_g, ln_b);

    // FFN1: h = relu(xb @ W1^T + b1) (256^2 8-phase, 512 blocks)
    gemm_256<<<dim3(512), dim3(512), 0, stream>>>(xbuf, W1b, b1, hb,
                                                  Mrows, PFq, 1);

    // FFN2, K=2048: y = h @ W2^T + b2 + xb, bf16 in place (256 blocks)
    gemm_n128<<<dim3(256), dim3(512), 0, stream>>>(hb, W2b, b2,
                                                   nullptr, nullptr, nullptr, xbuf,
                                                   512, 2048, 2);

    // LN2 -> out halves (overwrites the Xb scratch region of d_out)
    ln_b16_out<<<Mrows, blk, 0, stream>>>(xbuf, ln_g, ln_b, out);
}

// Round 11
// 304.242 us; speedup vs baseline: 2.0978x; 1.0118x over previous
//
#include <hip/hip_runtime.h>
#include <stdint.h>

// CrossAttention via linear-attention algebra, both halves merged to M=16384:
//   S = K1^T V1 + K2^T V2 (per b,h; 64x64), shared by both halves.
//   attn = Q @ S ; x = LN(inp + attn@Wo^T + bo) ; out = LN(x + FF(x))
// R20: restore R14 EXACTLY (best measured, 301.0us) — R15..R19 experiments
// (triple-buffer, algebraic fusion, mega-kernel, mode-3 residual) all measured
// neutral-to-worse and are reverted. Single change vs R14: both LN kernels
// replaced by the wave-per-row vectorized LN verified inside R18's mega
// (ushort8 16B/lane loads vs old 2B/lane scalars; 256 blocks x 512 thr).

#define Bq 4
#define Lq 2048
#define Dq 512
#define PFq 2048
#define Mrows 16384
#define MiBu 1048576ull
#define NSLICE 16

typedef __attribute__((ext_vector_type(8))) short frag_ab;
typedef __attribute__((ext_vector_type(4))) float frag_cd;
typedef __attribute__((ext_vector_type(8))) unsigned short ushort8v;

__device__ __forceinline__ unsigned short f2b(float f) {
    union { float f; uint32_t u; } x; x.f = f;
    uint32_t r = x.u + 0x7fffu + ((x.u >> 16) & 1u);
    return (unsigned short)(r >> 16);
}
__device__ __forceinline__ float b2f(unsigned short u) {
    union { uint32_t u; float f; } x; x.u = ((uint32_t)u) << 16;
    return x.f;
}

#define GLD16(g, l)                                                              \
    __builtin_amdgcn_global_load_lds(                                            \
        (const __attribute__((address_space(1))) void*)(const void*)(g),         \
        (__attribute__((address_space(3))) void*)(void*)(l), 16, 0, 0)

// One stage unit: 128 rows x 64 k-cols bf16 (2x global_load_lds_dwordx4/thread)
#define STG(BUFOFS, REGOFS, GB, ROWOFS, TILE, KS)                                \
    { GLD16((GB) + (size_t)(ROWOFS) * (KS) + (size_t)(TILE) * 64,                \
            Sh + (BUFOFS) + (REGOFS) + ld);                                      \
      GLD16((GB) + ((size_t)(ROWOFS) + 64) * (KS) + (size_t)(TILE) * 64,         \
            Sh + (BUFOFS) + (REGOFS) + ld + 4096); }

#define VMW(N) asm volatile("s_waitcnt vmcnt(" #N ")" ::: "memory")

// One phase: ds-read 2 M-frags (+8 B-frags if LOADB), issue stages, counted
// wait, barrier, 16 MFMA under setprio, barrier.
#define PHASE(CB, M0, LOADB, STAGE_STMT, WAIT_STMT)                              \
    {                                                                            \
        frag_ab a00 = *(const frag_ab*)&Sh[(CB) + (wm + (M0)*16 + lr) * 64 + xo0];      \
        frag_ab a01 = *(const frag_ab*)&Sh[(CB) + (wm + (M0)*16 + lr) * 64 + xo1];      \
        frag_ab a10 = *(const frag_ab*)&Sh[(CB) + (wm + (M0)*16 + 16 + lr) * 64 + xo0]; \
        frag_ab a11 = *(const frag_ab*)&Sh[(CB) + (wm + (M0)*16 + 16 + lr) * 64 + xo1]; \
        if (LOADB) {                                                             \
            _Pragma("unroll")                                                    \
            for (int j = 0; j < 4; ++j) {                                        \
                bf[j][0] = *(const frag_ab*)&Sh[(CB) + 16384 + (wn + j*16 + lr)*64 + xo0]; \
                bf[j][1] = *(const frag_ab*)&Sh[(CB) + 16384 + (wn + j*16 + lr)*64 + xo1]; \
            }                                                                    \
        }                                                                        \
        STAGE_STMT;                                                              \
        WAIT_STMT;                                                               \
        __builtin_amdgcn_sched_barrier(0);                                       \
        __builtin_amdgcn_s_barrier();                                            \
        asm volatile("s_waitcnt lgkmcnt(0)" ::: "memory");                       \
        __builtin_amdgcn_sched_barrier(0);                                       \
        __builtin_amdgcn_s_setprio(1);                                           \
        _Pragma("unroll")                                                        \
        for (int j = 0; j < 4; ++j) {                                            \
            acc[(M0)][j]   = __builtin_amdgcn_mfma_f32_16x16x32_bf16(a00, bf[j][0], acc[(M0)][j], 0,0,0);   \
            acc[(M0)][j]   = __builtin_amdgcn_mfma_f32_16x16x32_bf16(a01, bf[j][1], acc[(M0)][j], 0,0,0);   \
            acc[(M0)+1][j] = __builtin_amdgcn_mfma_f32_16x16x32_bf16(a10, bf[j][0], acc[(M0)+1][j], 0,0,0); \
            acc[(M0)+1][j] = __builtin_amdgcn_mfma_f32_16x16x32_bf16(a11, bf[j][1], acc[(M0)+1][j], 0,0,0); \
        }                                                                        \
        __builtin_amdgcn_s_setprio(0);                                           \
        __builtin_amdgcn_sched_barrier(0);                                       \
        __builtin_amdgcn_s_barrier();                                            \
        __builtin_amdgcn_sched_barrier(0);                                       \
    }

// ================== 256x256 8-phase bf16 GEMM (K=512 fixed) ==================
__global__ __launch_bounds__(512, 2) void gemm_256(
    const unsigned short* __restrict__ A, const unsigned short* __restrict__ Wt,
    const float* __restrict__ bias, unsigned short* __restrict__ outB,
    int M, int N, int relu)
{
    __shared__ __align__(16) unsigned short Sh[65536];   // 128 KiB
    const int tid = threadIdx.x;
    const int lane = tid & 63;
    const int w = tid >> 6;              // 0..7
    const int wm = (w >> 2) * 128;       // 0 / 128
    const int wn = (w & 3) * 64;         // 0..192
    const int lr = lane & 15;
    const int quad = lane >> 4;
    const int xo0 = ((quad ^ (lr & 7)) << 3);
    const int xo1 = (((4 | quad) ^ (lr & 7)) << 3);

    // 2D XCD chunking
    const int b0 = blockIdx.x;
    const int xcd = b0 & 7, slot = b0 >> 3;
    const int mloc = (M >> 8) >> 3;
    const size_t bm = (size_t)(xcd * mloc + slot % mloc) * 256;
    const size_t bn = (size_t)(slot / mloc) * 256;

    const int ar = tid >> 3;
    const int sw = ((tid & 7) ^ (ar & 7)) << 3;
    const unsigned short* Ag = A  + (bm + ar) * (size_t)512 + sw;
    const unsigned short* Bg = Wt + (bn + ar) * (size_t)512 + sw;
    const int ld = tid * 8;

    frag_cd acc[8][4] = {};
    frag_ab bf[4][2];

    STG(0,     16384, Bg, 0,   0, 512);
    STG(0,     24576, Bg, 128, 0, 512);
    STG(0,     0,     Ag, 0,   0, 512);
    STG(0,     8192,  Ag, 128, 0, 512);
    STG(32768, 16384, Bg, 0,   1, 512);
    STG(32768, 24576, Bg, 128, 1, 512);
    VMW(4);
    __builtin_amdgcn_sched_barrier(0);
    __builtin_amdgcn_s_barrier();
    __builtin_amdgcn_sched_barrier(0);

    for (int I = 0; I < 3; ++I) {
        const int tb = 2 * I + 1, tc = 2 * I + 2, td = 2 * I + 3;
        PHASE(0,     0, 1, STG(32768, 0,     Ag, 0,   tb, 512), (void)0);
        PHASE(0,     2, 0, STG(32768, 8192,  Ag, 128, tb, 512), (void)0);
        PHASE(0,     4, 0, STG(0,     16384, Bg, 0,   tc, 512), (void)0);
        PHASE(0,     6, 0, STG(0,     24576, Bg, 128, tc, 512), VMW(4));
        PHASE(32768, 0, 1, STG(0,     0,     Ag, 0,   tc, 512), (void)0);
        PHASE(32768, 2, 0, STG(0,     8192,  Ag, 128, tc, 512), (void)0);
        PHASE(32768, 4, 0, STG(32768, 16384, Bg, 0,   td, 512), (void)0);
        PHASE(32768, 6, 0, STG(32768, 24576, Bg, 128, td, 512), VMW(4));
    }
    PHASE(0,     0, 1, STG(32768, 0,    Ag, 0,   7, 512), (void)0);
    PHASE(0,     2, 0, STG(32768, 8192, Ag, 128, 7, 512), (void)0);
    PHASE(0,     4, 0, (void)0, (void)0);
    PHASE(0,     6, 0, (void)0, VMW(0));
    PHASE(32768, 0, 1, (void)0, (void)0);
    PHASE(32768, 2, 0, (void)0, (void)0);
    PHASE(32768, 4, 0, (void)0, (void)0);
    PHASE(32768, 6, 0, (void)0, (void)0);

    float bv[4];
#pragma unroll
    for (int j = 0; j < 4; ++j) bv[j] = bias[(int)bn + wn + j * 16 + lr];
    unsigned short* Cs = Sh + w * 8192;
#pragma unroll
    for (int m = 0; m < 8; ++m)
#pragma unroll
        for (int j = 0; j < 4; ++j)
#pragma unroll
            for (int r = 0; r < 4; ++r) {
                float v = acc[m][j][r] + bv[j];
                if (relu) v = fmaxf(v, 0.f);
                Cs[(m * 16 + quad * 4 + r) * 64 + j * 16 + lr] = f2b(v);
            }
    const int rl = lane >> 3, c8 = (lane & 7) * 8;
#pragma unroll
    for (int k = 0; k < 16; ++k) {
        const int row = rl + k * 8;
        ushort8v val = *(const ushort8v*)&Cs[row * 64 + c8];
        *(ushort8v*)(outB + (size_t)(bm + wm + row) * N + bn + wn + c8) = val;
    }
}

// ======= 256x128 4-phase GEMM, runtime N (out stride) and K ==================
// mode 0: outB = A@W^T + bias ; 1: + f32 residual resA/resB (rows <8192 /
// >=8192) ; 2: + b2f(outB) in place.
__global__ __launch_bounds__(512, 2) void gemm_n128(
    const unsigned short* __restrict__ A, const unsigned short* __restrict__ Wt,
    const float* __restrict__ bias,
    const float* __restrict__ resA, const float* __restrict__ resB,
    unsigned short* __restrict__ outB, int N, int K, int mode)
{
    __shared__ __align__(16) unsigned short Sh[49152];   // 96 KiB
    const int tid = threadIdx.x;
    const int lane = tid & 63;
    const int w = tid >> 6;              // 0..7
    const int wm = (w >> 1) * 64;        // 0/64/128/192
    const int wn = (w & 1) * 64;         // 0/64
    const int lr = lane & 15;
    const int quad = lane >> 4;
    const int xo0 = ((quad ^ (lr & 7)) << 3);
    const int xo1 = (((4 | quad) ^ (lr & 7)) << 3);

    // 2D XCD chunking: xcd owns 8 consecutive m-tiles x all n-tiles.
    const int b0 = blockIdx.x;
    const int xcd = b0 & 7, slot = b0 >> 3;
    const size_t bm = (size_t)(xcd * 8 + (slot & 7)) * 256;
    const size_t bn = (size_t)(slot >> 3) * 128;

    const int ar = tid >> 3;
    const int sw = ((tid & 7) ^ (ar & 7)) << 3;
    const unsigned short* Ag = A  + (bm + ar) * (size_t)K + sw;
    const unsigned short* Bg = Wt + (bn + ar) * (size_t)K + sw;
    const int ld = tid * 8;

    frag_cd acc[4][4] = {};
    frag_ab bf[4][2];

    // prologue: aB aA0 aA1 bB ; wait all but bB
    STG(0,     16384, Bg, 0,   0, K);
    STG(0,     0,     Ag, 0,   0, K);
    STG(0,     8192,  Ag, 128, 0, K);
    STG(24576, 16384, Bg, 0,   1, K);
    VMW(2);
    __builtin_amdgcn_sched_barrier(0);
    __builtin_amdgcn_s_barrier();
    __builtin_amdgcn_sched_barrier(0);

    const int nIter = K >> 7;            // 2 K-tiles per iteration
    for (int I = 0; I < nIter - 1; ++I) {
        const int tb = 2 * I + 1, tc = 2 * I + 2, td = 2 * I + 3;
        PHASE(0,     0, 1, { STG(24576, 0, Ag, 0, tb, K); STG(24576, 8192, Ag, 128, tb, K); }, (void)0);
        PHASE(0,     2, 0, STG(0, 16384, Bg, 0, tc, K), VMW(2));
        PHASE(24576, 0, 1, { STG(0, 0, Ag, 0, tc, K); STG(0, 8192, Ag, 128, tc, K); }, (void)0);
        PHASE(24576, 2, 0, STG(24576, 16384, Bg, 0, td, K), VMW(2));
    }
    {   // tail: computes tiles 2(nIter-1), 2nIter-1; only b's A left to stage
        const int tb = (K >> 6) - 1;
        PHASE(0,     0, 1, { STG(24576, 0, Ag, 0, tb, K); STG(24576, 8192, Ag, 128, tb, K); }, (void)0);
        PHASE(0,     2, 0, (void)0, VMW(0));
        PHASE(24576, 0, 1, (void)0, (void)0);
        PHASE(24576, 2, 0, (void)0, (void)0);
    }

    float bv[4];
#pragma unroll
    for (int j = 0; j < 4; ++j) bv[j] = bias[(int)bn + wn + j * 16 + lr];
    unsigned short* Cs = Sh + w * 4096;
#pragma unroll
    for (int m = 0; m < 4; ++m)
#pragma unroll
        for (int j = 0; j < 4; ++j)
#pragma unroll
            for (int r = 0; r < 4; ++r)
                Cs[(m * 16 + quad * 4 + r) * 64 + j * 16 + lr] = f2b(acc[m][j][r] + bv[j]);
    const int rl = lane >> 3, c8 = (lane & 7) * 8;
#pragma unroll
    for (int k = 0; k < 8; ++k) {
        const int row = rl + k * 8;
        const int grow = (int)bm + wm + row;
        const size_t idx = (size_t)grow * N + bn + wn + c8;
        ushort8v val = *(const ushort8v*)&Cs[row * 64 + c8];
        if (mode == 0) {
            *(ushort8v*)(outB + idx) = val;
            continue;
        }
        float vv[8];
#pragma unroll
        for (int t2 = 0; t2 < 8; ++t2) vv[t2] = b2f(val[t2]);
        if (mode == 1) {
            const float* rp = (grow < 8192) ? resA + idx : resB + idx - (size_t)8192 * N;
            float4 ra = *(const float4*)(rp);
            float4 rb = *(const float4*)(rp + 4);
            vv[0] += ra.x; vv[1] += ra.y; vv[2] += ra.z; vv[3] += ra.w;
            vv[4] += rb.x; vv[5] += rb.y; vv[6] += rb.z; vv[7] += rb.w;
        } else {
            ushort8v old = *(const ushort8v*)(outB + idx);
#pragma unroll
            for (int t2 = 0; t2 < 8; ++t2) vv[t2] += b2f(old[t2]);
        }
        ushort8v o;
#pragma unroll
        for (int t2 = 0; t2 < 8; ++t2) o[t2] = f2b(vv[t2]);
        *(ushort8v*)(outB + idx) = o;
    }
}

// -------- merged fp32->bf16 converts + QKV bias concat --------
__global__ __launch_bounds__(256) void convert_all(
    const float* __restrict__ Wq, const float* __restrict__ Wk,
    const float* __restrict__ Wv, const float* __restrict__ Wo,
    const float* __restrict__ W1, const float* __restrict__ W2,
    const float* __restrict__ question, const float* __restrict__ query,
    const float* __restrict__ bqp, const float* __restrict__ bkp,
    const float* __restrict__ bvp,
    unsigned short* __restrict__ Wqkvb, unsigned short* __restrict__ Wob,
    unsigned short* __restrict__ W1b, unsigned short* __restrict__ W2b,
    unsigned short* __restrict__ Xb, float* __restrict__ bqkv)
{
    const int b = blockIdx.x;
    const float* src; unsigned short* dst; size_t off;
    if (b < 256)        { src = Wq; dst = Wqkvb;          off = (size_t)b * 1024; }
    else if (b < 512)   { src = Wk; dst = Wqkvb + 262144; off = (size_t)(b - 256) * 1024; }
    else if (b < 768)   { src = Wv; dst = Wqkvb + 524288; off = (size_t)(b - 512) * 1024; }
    else if (b < 1024)  { src = Wo; dst = Wob;            off = (size_t)(b - 768) * 1024; }
    else if (b < 2048)  { src = W1; dst = W1b;            off = (size_t)(b - 1024) * 1024; }
    else if (b < 3072)  { src = W2; dst = W2b;            off = (size_t)(b - 2048) * 1024; }
    else if (b < 7168)  { src = question; dst = Xb;       off = (size_t)(b - 3072) * 1024; }
    else if (b < 11264) { src = query; dst = Xb + 4194304; off = (size_t)(b - 7168) * 1024; }
    else {
        const int n = (b - 11264) * 256 + threadIdx.x;   // 0..1535
        bqkv[n] = (n < 512) ? bqp[n] : (n < 1024) ? bkp[n - 512] : bvp[n - 1024];
        return;
    }
    const size_t idx = off + threadIdx.x * 4;
    float4 v = *(const float4*)(src + idx);
    ushort4 o;
    o.x = f2b(v.x); o.y = f2b(v.y); o.z = f2b(v.z); o.w = f2b(v.w);
    *(ushort4*)(dst + idx) = o;
}

// ------- Spart[bh][slice] = sum over 256 l-rows of K^T outer V (merged QKV) ----
__global__ __launch_bounds__(256) void s_kernel(
    const unsigned short* __restrict__ QKV, float* __restrict__ Spart)
{
    const int bh = blockIdx.x;           // 0..31
    const int sl = blockIdx.y;           // 0..NSLICE-1
    const int b = bh >> 3, h = bh & 7;
    const int pass = sl >> 3;
    const int l0 = (sl & 7) * 256;
    __shared__ float Ks[64][64];
    __shared__ float Vs[64][64];
    const int tid = threadIdx.x;
    const int tx = tid & 15, ty = tid >> 4;
    const int srow = tid >> 3;
    const int scol = (tid & 7) * 8;
    const size_t rowbase = (size_t)pass * 8192 + (size_t)b * Lq + l0;

    float acc[4][4] = {};

    for (int t0 = 0; t0 < 256; t0 += 64) {
        const unsigned short* kp0 = QKV + (rowbase + t0 + srow) * 1536 + 512 + h * 64 + scol;
        const unsigned short* kp1 = kp0 + (size_t)32 * 1536;
        ushort8v k0 = *(const ushort8v*)kp0;
        ushort8v v0 = *(const ushort8v*)(kp0 + 512);
        ushort8v k1 = *(const ushort8v*)kp1;
        ushort8v v1 = *(const ushort8v*)(kp1 + 512);
        __syncthreads();
#pragma unroll
        for (int e = 0; e < 8; ++e) {
            Ks[srow][scol + e]      = b2f(k0[e]);
            Vs[srow][scol + e]      = b2f(v0[e]);
            Ks[srow + 32][scol + e] = b2f(k1[e]);
            Vs[srow + 32][scol + e] = b2f(v1[e]);
        }
        __syncthreads();
#pragma unroll 4
        for (int rr = 0; rr < 64; ++rr) {
            const float4 kf = *(const float4*)&Ks[rr][ty * 4];
            const float4 vf = *(const float4*)&Vs[rr][tx * 4];
            acc[0][0] = fmaf(kf.x, vf.x, acc[0][0]);
            acc[0][1] = fmaf(kf.x, vf.y, acc[0][1]);
            acc[0][2] = fmaf(kf.x, vf.z, acc[0][2]);
            acc[0][3] = fmaf(kf.x, vf.w, acc[0][3]);
            acc[1][0] = fmaf(kf.y, vf.x, acc[1][0]);
            acc[1][1] = fmaf(kf.y, vf.y, acc[1][1]);
            acc[1][2] = fmaf(kf.y, vf.z, acc[1][2]);
            acc[1][3] = fmaf(kf.y, vf.w, acc[1][3]);
            acc[2][0] = fmaf(kf.z, vf.x, acc[2][0]);
            acc[2][1] = fmaf(kf.z, vf.y, acc[2][1]);
            acc[2][2] = fmaf(kf.z, vf.z, acc[2][2]);
            acc[2][3] = fmaf(kf.z, vf.w, acc[2][3]);
            acc[3][0] = fmaf(kf.w, vf.x, acc[3][0]);
            acc[3][1] = fmaf(kf.w, vf.y, acc[3][1]);
            acc[3][2] = fmaf(kf.w, vf.z, acc[3][2]);
            acc[3][3] = fmaf(kf.w, vf.w, acc[3][3]);
        }
    }

    float* Sp = Spart + ((size_t)bh * NSLICE + sl) * 4096;
#pragma unroll
    for (int i = 0; i < 4; ++i) {
        float4 o = make_float4(acc[i][0], acc[i][1], acc[i][2], acc[i][3]);
        *(float4*)(Sp + (ty * 4 + i) * 64 + tx * 4) = o;
    }
}

// ------- reduce NSLICE partials -> Sbt bf16, B-layout [bh][khalf][n][kj] -------
__global__ __launch_bounds__(256) void sbt_convert(
    const float* __restrict__ Spart, unsigned short* __restrict__ Sbt)
{
    const int bh = blockIdx.x;
    const int uo = blockIdx.y;           // 0..3
    const float* Sp = Spart + (size_t)bh * (NSLICE * 4096);
    unsigned short* Dp = Sbt + (size_t)bh * 4096;
    const int t = threadIdx.x;
#pragma unroll
    for (int u = 0; u < 4; ++u) {
        const int d = (uo * 4 + u) * 256 + t;
        float v = 0.f;
#pragma unroll
        for (int s = 0; s < NSLICE; ++s) v += Sp[(size_t)s * 4096 + d];
        const int row = d >> 6, col = d & 63;
        Dp[(row >> 5) * 2048 + col * 32 + (row & 31)] = f2b(v);
    }
}

// ------- attn = Q @ S_bh via MFMA; block: 128 rows x 64 cols (one head) -------
__global__ __launch_bounds__(256) void attn_mfma(
    const unsigned short* __restrict__ QKV, const unsigned short* __restrict__ Sbt,
    unsigned short* __restrict__ Ob)
{
    __shared__ __align__(16) unsigned short Sh[2 * 128 * 32 + 2 * 64 * 32];
    unsigned short* At = Sh;
    unsigned short* Bt = Sh + 2 * 128 * 32;
    const int h = blockIdx.x;
    const int rbase = blockIdx.y * 128;
    const int b = (rbase >> 11) & 3;
    const int bh = b * 8 + h;
    const int tid = threadIdx.x;
    const int lane = tid & 63;
    const int w = tid >> 6;
    const int lr = lane & 15;
    const int quad = lane >> 4;

    {
        const int rloc = tid >> 2, c8 = (tid & 3) * 8;
#pragma unroll
        for (int it = 0; it < 4; ++it) {
            const int kk = it & 1, rh = it >> 1;
            const unsigned short* g = QKV +
                ((size_t)rbase + rh * 64 + rloc) * 1536 + h * 64 + kk * 32 + c8;
            GLD16(g, At + kk * 4096 + rh * 2048 + w * 512);
        }
        const unsigned short* Sg = Sbt + (size_t)bh * 4096 + tid * 8;
#pragma unroll
        for (int bi = 0; bi < 2; ++bi)
            GLD16(Sg + bi * 2048, Bt + bi * 2048 + w * 512);
    }
    __syncthreads();

    frag_cd acc[2][4] = {};
#pragma unroll
    for (int kk = 0; kk < 2; ++kk) {
        frag_ab a[2], bfr[4];
#pragma unroll
        for (int i = 0; i < 2; ++i)
            a[i] = *(const frag_ab*)&At[kk * 4096 + (w * 32 + i * 16 + lr) * 32 + quad * 8];
#pragma unroll
        for (int j = 0; j < 4; ++j)
            bfr[j] = *(const frag_ab*)&Bt[kk * 2048 + (j * 16 + lr) * 32 + quad * 8];
#pragma unroll
        for (int i = 0; i < 2; ++i)
#pragma unroll
            for (int j = 0; j < 4; ++j)
                acc[i][j] = __builtin_amdgcn_mfma_f32_16x16x32_bf16(a[i], bfr[j], acc[i][j], 0, 0, 0);
    }

    __syncthreads();
    unsigned short* Cs = Sh + w * 2048;
#pragma unroll
    for (int i = 0; i < 2; ++i)
#pragma unroll
        for (int j = 0; j < 4; ++j)
#pragma unroll
            for (int r = 0; r < 4; ++r)
                Cs[(i * 16 + quad * 4 + r) * 64 + j * 16 + lr] = f2b(acc[i][j][r]);
    const int rl = lane >> 3;
    const int c8o = (lane & 7) * 8;
#pragma unroll
    for (int k = 0; k < 4; ++k) {
        const int row = rl + k * 8;
        ushort8v val = *(const ushort8v*)&Cs[row * 64 + c8o];
        *(ushort8v*)(Ob + (size_t)(rbase + w * 32 + row) * 512 + h * 64 + c8o) = val;
    }
}

// ------- LN wave-per-row, ushort8 vectorized (verified in R18 mega) ----------
// out==null: bf16 in place ; else: f32 half-columns (merged rows).
// grid 256 blocks x 512 threads; block handles rows [blk*64, blk*64+64).
__global__ __launch_bounds__(512) void ln_fast(
    unsigned short* __restrict__ Y, const float* __restrict__ g,
    const float* __restrict__ bta, float* __restrict__ out)
{
    const int blk = blockIdx.x;
    const int tid = threadIdx.x;
    const int wv = tid >> 6, lane = tid & 63;
    const int c0 = lane * 8;
    float4 ga = *(const float4*)(g + c0), gb = *(const float4*)(g + c0 + 4);
    float4 ba = *(const float4*)(bta + c0), bb = *(const float4*)(bta + c0 + 4);
    const float gv[8] = {ga.x, ga.y, ga.z, ga.w, gb.x, gb.y, gb.z, gb.w};
    const float bv[8] = {ba.x, ba.y, ba.z, ba.w, bb.x, bb.y, bb.z, bb.w};
#pragma unroll
    for (int r = 0; r < 8; ++r) {
        const int row = blk * 64 + r * 8 + wv;
        unsigned short* yr = Y + (size_t)row * Dq;
        ushort8v v = *(const ushort8v*)(yr + c0);
        float f[8];
        float s = 0.f;
#pragma unroll
        for (int e = 0; e < 8; ++e) { f[e] = b2f(v[e]); s += f[e]; }
#pragma unroll
        for (int off = 32; off; off >>= 1) s += __shfl_xor(s, off, 64);
        const float mean = s * (1.f / Dq);
        float q = 0.f;
#pragma unroll
        for (int e = 0; e < 8; ++e) { f[e] -= mean; q += f[e] * f[e]; }
#pragma unroll
        for (int off = 32; off; off >>= 1) q += __shfl_xor(q, off, 64);
        const float rstd = rsqrtf(q * (1.f / Dq) + 1e-5f);
        if (out) {
            const int half = row >> 13, br = row & 8191;
            float* orow = out + (size_t)br * 1024 + half * 512 + c0;
            float4 o0, o1;
            o0.x = f[0] * rstd * gv[0] + bv[0];
            o0.y = f[1] * rstd * gv[1] + bv[1];
            o0.z = f[2] * rstd * gv[2] + bv[2];
            o0.w = f[3] * rstd * gv[3] + bv[3];
            o1.x = f[4] * rstd * gv[4] + bv[4];
            o1.y = f[5] * rstd * gv[5] + bv[5];
            o1.z = f[6] * rstd * gv[6] + bv[6];
            o1.w = f[7] * rstd * gv[7] + bv[7];
            *(float4*)orow = o0;
            *(float4*)(orow + 4) = o1;
        } else {
            ushort8v o;
#pragma unroll
            for (int e = 0; e < 8; ++e) o[e] = f2b(f[e] * rstd * gv[e] + bv[e]);
            *(ushort8v*)(yr + c0) = o;
        }
    }
}

extern "C" void kernel_launch(void* const* d_in, const int* in_sizes, int n_in,
                              void* d_out, int out_size, void* d_ws, size_t ws_size,
                              hipStream_t stream)
{
    const float* question = (const float*)d_in[0];
    const float* query    = (const float*)d_in[1];
    const float* Wq = (const float*)d_in[2];  const float* bqp = (const float*)d_in[3];
    const float* Wk = (const float*)d_in[4];  const float* bkp = (const float*)d_in[5];
    const float* Wv = (const float*)d_in[6];  const float* bvp = (const float*)d_in[7];
    const float* Wo = (const float*)d_in[8];  const float* bo  = (const float*)d_in[9];
    const float* ln_g = (const float*)d_in[10]; const float* ln_b = (const float*)d_in[11];
    const float* W1 = (const float*)d_in[12]; const float* b1 = (const float*)d_in[13];
    const float* W2 = (const float*)d_in[14]; const float* b2 = (const float*)d_in[15];
    float* out = (float*)d_out;
    char* ws = (char*)d_ws;

    // ---- workspace (~87 MiB), exact R14 layout ----
    unsigned short* QKVb  = (unsigned short*)(ws);               // [16384][1536] 48 MiB
    unsigned short* attnb = (unsigned short*)(ws + 48 * MiBu);   // 16 MiB
    float* Spart          = (float*)(ws + 48 * MiBu);            // 8 MiB, dead before attnb
    unsigned short* Xb    = (unsigned short*)(ws + 64 * MiBu);   // 16 MiB
    unsigned short* xbuf  = (unsigned short*)(ws + 64 * MiBu);   // y0b -> xb -> y (aliases Xb)
    unsigned short* hb    = (unsigned short*)(ws);               // [16384][2048] 64 MiB
    char* wp = ws + 80 * MiBu + 524288;
    unsigned short* Wqkvb = (unsigned short*)wp;  wp += 1536 * 512 * 2;
    unsigned short* Wob   = (unsigned short*)wp;  wp += 512 * 512 * 2;
    unsigned short* W1b   = (unsigned short*)wp;  wp += 2048 * 512 * 2;
    unsigned short* W2b   = (unsigned short*)wp;  wp += 512 * 2048 * 2;
    unsigned short* Sbt   = (unsigned short*)wp;  wp += 32 * 4096 * 2;
    float* bqkv           = (float*)wp;

    dim3 blk(256);

    convert_all<<<11270, blk, 0, stream>>>(Wq, Wk, Wv, Wo, W1, W2, question, query,
                                           bqp, bkp, bvp,
                                           Wqkvb, Wob, W1b, W2b, Xb, bqkv);

    // QKV: [16384,512]@[1536,512]^T -> bf16 (256x128 4-phase; 768 blocks = 3 rounds)
    gemm_n128<<<dim3(768), dim3(512), 0, stream>>>(Xb, Wqkvb, bqkv,
                                                   nullptr, nullptr, QKVb,
                                                   1536, 512, 0);

    // S partials (fp32, no atomics) -> reduce+pack bf16 B-layout; attn via MFMA
    s_kernel<<<dim3(32, NSLICE), blk, 0, stream>>>(QKVb, Spart);
    sbt_convert<<<dim3(32, 4), blk, 0, stream>>>(Spart, Sbt);
    attn_mfma<<<dim3(8, 128), blk, 0, stream>>>(QKVb, Sbt, attnb);

    // o-proj + residual(inputs f32) + bo -> bf16 y0b (256 blocks)
    gemm_n128<<<dim3(256), dim3(512), 0, stream>>>(attnb, Wob, bo,
                                                   question, query, xbuf,
                                                   512, 512, 1);

    // LN1 in place: xb = LN(y0b)  (vectorized wave-per-row)
    ln_fast<<<dim3(256), dim3(512), 0, stream>>>(xbuf, ln_g, ln_b, nullptr);

    // FFN1: h = relu(xb @ W1^T + b1) (256^2 8-phase, 512 blocks)
    gemm_256<<<dim3(512), dim3(512), 0, stream>>>(xbuf, W1b, b1, hb,
                                                  Mrows, PFq, 1);

    // FFN2, K=2048: y = h @ W2^T + b2 + xb, bf16 in place (256 blocks)
    gemm_n128<<<dim3(256), dim3(512), 0, stream>>>(hb, W2b, b2,
                                                   nullptr, nullptr, xbuf,
                                                   512, 2048, 2);

    // LN2 -> out halves (vectorized wave-per-row)
    ln_fast<<<dim3(256), dim3(512), 0, stream>>>(xbuf, ln_g, ln_b, out);
}

// Round 12
// 294.546 us; speedup vs baseline: 2.1669x; 1.0329x over previous
//
#include <hip/hip_runtime.h>
#include <stdint.h>

// CrossAttention via linear-attention algebra, both halves merged to M=16384:
//   S = K1^T V1 + K2^T V2 (per b,h; 64x64), shared by both halves.
//   attn = Q @ S ; x = LN(inp + attn@Wo^T + bo) ; out = LN(x + FF(x))
// R21: FFN1 moved to gemm_128 — 128x128 tile, 4-phase counted-vmcnt schedule,
// LDS 64 KiB -> 2 blocks/CU (__launch_bounds__(256,2)). Rationale: all phased
// kernels so far use >=96 KiB LDS = 1 block/CU, so every barrier drain idles
// the whole CU; m114 shows co-resident blocks overlap MFMA/memory for free.
// Counted-vmcnt + multi-block residency is the one untested combination.
// gemm_256 deleted (dead). Rest identical to R20 (301-304us plateau config).

#define Bq 4
#define Lq 2048
#define Dq 512
#define PFq 2048
#define Mrows 16384
#define MiBu 1048576ull
#define NSLICE 16

typedef __attribute__((ext_vector_type(8))) short frag_ab;
typedef __attribute__((ext_vector_type(4))) float frag_cd;
typedef __attribute__((ext_vector_type(8))) unsigned short ushort8v;

__device__ __forceinline__ unsigned short f2b(float f) {
    union { float f; uint32_t u; } x; x.f = f;
    uint32_t r = x.u + 0x7fffu + ((x.u >> 16) & 1u);
    return (unsigned short)(r >> 16);
}
__device__ __forceinline__ float b2f(unsigned short u) {
    union { uint32_t u; float f; } x; x.u = ((uint32_t)u) << 16;
    return x.f;
}

#define GLD16(g, l)                                                              \
    __builtin_amdgcn_global_load_lds(                                            \
        (const __attribute__((address_space(1))) void*)(const void*)(g),         \
        (__attribute__((address_space(3))) void*)(void*)(l), 16, 0, 0)

// Stage unit (512-thread kernels): 128 rows x 64 k-cols bf16
#define STG(BUFOFS, REGOFS, GB, ROWOFS, TILE, KS)                                \
    { GLD16((GB) + (size_t)(ROWOFS) * (KS) + (size_t)(TILE) * 64,                \
            Sh + (BUFOFS) + (REGOFS) + ld);                                      \
      GLD16((GB) + ((size_t)(ROWOFS) + 64) * (KS) + (size_t)(TILE) * 64,         \
            Sh + (BUFOFS) + (REGOFS) + ld + 4096); }

// Stage unit (256-thread kernel): 64 rows x 64 k-cols bf16
#define STGH(BUFOFS, REGOFS, GB, ROWOFS, TILE, KS)                               \
    { GLD16((GB) + (size_t)(ROWOFS) * (KS) + (size_t)(TILE) * 64,                \
            Sh + (BUFOFS) + (REGOFS) + ld);                                      \
      GLD16((GB) + ((size_t)(ROWOFS) + 32) * (KS) + (size_t)(TILE) * 64,         \
            Sh + (BUFOFS) + (REGOFS) + ld + 2048); }

#define VMW(N) asm volatile("s_waitcnt vmcnt(" #N ")" ::: "memory")

// Phase (B region at CB+16384, for 256-wide B tiles)
#define PHASE(CB, M0, LOADB, STAGE_STMT, WAIT_STMT)                              \
    {                                                                            \
        frag_ab a00 = *(const frag_ab*)&Sh[(CB) + (wm + (M0)*16 + lr) * 64 + xo0];      \
        frag_ab a01 = *(const frag_ab*)&Sh[(CB) + (wm + (M0)*16 + lr) * 64 + xo1];      \
        frag_ab a10 = *(const frag_ab*)&Sh[(CB) + (wm + (M0)*16 + 16 + lr) * 64 + xo0]; \
        frag_ab a11 = *(const frag_ab*)&Sh[(CB) + (wm + (M0)*16 + 16 + lr) * 64 + xo1]; \
        if (LOADB) {                                                             \
            _Pragma("unroll")                                                    \
            for (int j = 0; j < 4; ++j) {                                        \
                bf[j][0] = *(const frag_ab*)&Sh[(CB) + 16384 + (wn + j*16 + lr)*64 + xo0]; \
                bf[j][1] = *(const frag_ab*)&Sh[(CB) + 16384 + (wn + j*16 + lr)*64 + xo1]; \
            }                                                                    \
        }                                                                        \
        STAGE_STMT;                                                              \
        WAIT_STMT;                                                               \
        __builtin_amdgcn_sched_barrier(0);                                       \
        __builtin_amdgcn_s_barrier();                                            \
        asm volatile("s_waitcnt lgkmcnt(0)" ::: "memory");                       \
        __builtin_amdgcn_sched_barrier(0);                                       \
        __builtin_amdgcn_s_setprio(1);                                           \
        _Pragma("unroll")                                                        \
        for (int j = 0; j < 4; ++j) {                                            \
            acc[(M0)][j]   = __builtin_amdgcn_mfma_f32_16x16x32_bf16(a00, bf[j][0], acc[(M0)][j], 0,0,0);   \
            acc[(M0)][j]   = __builtin_amdgcn_mfma_f32_16x16x32_bf16(a01, bf[j][1], acc[(M0)][j], 0,0,0);   \
            acc[(M0)+1][j] = __builtin_amdgcn_mfma_f32_16x16x32_bf16(a10, bf[j][0], acc[(M0)+1][j], 0,0,0); \
            acc[(M0)+1][j] = __builtin_amdgcn_mfma_f32_16x16x32_bf16(a11, bf[j][1], acc[(M0)+1][j], 0,0,0); \
        }                                                                        \
        __builtin_amdgcn_s_setprio(0);                                           \
        __builtin_amdgcn_sched_barrier(0);                                       \
        __builtin_amdgcn_s_barrier();                                            \
        __builtin_amdgcn_sched_barrier(0);                                       \
    }

// Phase (B region at CB+8192, for 128-wide A/B tiles)
#define PHASE128(CB, M0, LOADB, STAGE_STMT, WAIT_STMT)                           \
    {                                                                            \
        frag_ab a00 = *(const frag_ab*)&Sh[(CB) + (wm + (M0)*16 + lr) * 64 + xo0];      \
        frag_ab a01 = *(const frag_ab*)&Sh[(CB) + (wm + (M0)*16 + lr) * 64 + xo1];      \
        frag_ab a10 = *(const frag_ab*)&Sh[(CB) + (wm + (M0)*16 + 16 + lr) * 64 + xo0]; \
        frag_ab a11 = *(const frag_ab*)&Sh[(CB) + (wm + (M0)*16 + 16 + lr) * 64 + xo1]; \
        if (LOADB) {                                                             \
            _Pragma("unroll")                                                    \
            for (int j = 0; j < 4; ++j) {                                        \
                bf[j][0] = *(const frag_ab*)&Sh[(CB) + 8192 + (wn + j*16 + lr)*64 + xo0]; \
                bf[j][1] = *(const frag_ab*)&Sh[(CB) + 8192 + (wn + j*16 + lr)*64 + xo1]; \
            }                                                                    \
        }                                                                        \
        STAGE_STMT;                                                              \
        WAIT_STMT;                                                               \
        __builtin_amdgcn_sched_barrier(0);                                       \
        __builtin_amdgcn_s_barrier();                                            \
        asm volatile("s_waitcnt lgkmcnt(0)" ::: "memory");                       \
        __builtin_amdgcn_sched_barrier(0);                                       \
        __builtin_amdgcn_s_setprio(1);                                           \
        _Pragma("unroll")                                                        \
        for (int j = 0; j < 4; ++j) {                                            \
            acc[(M0)][j]   = __builtin_amdgcn_mfma_f32_16x16x32_bf16(a00, bf[j][0], acc[(M0)][j], 0,0,0);   \
            acc[(M0)][j]   = __builtin_amdgcn_mfma_f32_16x16x32_bf16(a01, bf[j][1], acc[(M0)][j], 0,0,0);   \
            acc[(M0)+1][j] = __builtin_amdgcn_mfma_f32_16x16x32_bf16(a10, bf[j][0], acc[(M0)+1][j], 0,0,0); \
            acc[(M0)+1][j] = __builtin_amdgcn_mfma_f32_16x16x32_bf16(a11, bf[j][1], acc[(M0)+1][j], 0,0,0); \
        }                                                                        \
        __builtin_amdgcn_s_setprio(0);                                           \
        __builtin_amdgcn_sched_barrier(0);                                       \
        __builtin_amdgcn_s_barrier();                                            \
        __builtin_amdgcn_sched_barrier(0);                                       \
    }

// ===== 128x128 4-phase GEMM, 2 blocks/CU (64 KiB LDS), K=512, bias+relu =====
// grid (M/128)*(N/128), 256 threads = 4 waves (2Mx2N), per-wave 64x64.
// Ledger (stage unit = 2xSTGH = 4 loads): prologue aA,aB(buf0) + bB(buf1),
// VMW(4). Iter: P0 stage bA | P1 stage cB + VMW(4) | P2 stage cA | P3 stage
// dB + VMW(4). Tail peeled, VMW(0) at P1.
__global__ __launch_bounds__(256, 2) void gemm_128(
    const unsigned short* __restrict__ A, const unsigned short* __restrict__ Wt,
    const float* __restrict__ bias, unsigned short* __restrict__ outB,
    int M, int N, int relu)
{
    __shared__ __align__(16) unsigned short Sh[32768];   // 64 KiB
    const int tid = threadIdx.x;
    const int lane = tid & 63;
    const int w = tid >> 6;              // 0..3
    const int wm = (w >> 1) * 64;        // 0/64
    const int wn = (w & 1) * 64;         // 0/64
    const int lr = lane & 15;
    const int quad = lane >> 4;
    const int xo0 = ((quad ^ (lr & 7)) << 3);
    const int xo1 = (((4 | quad) ^ (lr & 7)) << 3);

    // 2D XCD chunking: xcd owns mloc consecutive m-tiles x all n-tiles.
    const int b0 = blockIdx.x;
    const int xcd = b0 & 7, slot = b0 >> 3;
    const int mloc = (M >> 7) >> 3;
    const size_t bm = (size_t)(xcd * mloc + slot % mloc) * 128;
    const size_t bn = (size_t)(slot / mloc) * 128;

    const int ar = tid >> 3;                         // 0..31
    const int sw = ((tid & 7) ^ (ar & 7)) << 3;
    const unsigned short* Ag = A  + (bm + ar) * (size_t)512 + sw;
    const unsigned short* Bg = Wt + (bn + ar) * (size_t)512 + sw;
    const int ld = tid * 8;                          // 16B/lane, 32 rows/issue

    frag_cd acc[4][4] = {};
    frag_ab bf[4][2];

    // prologue: buf0 = tile0 A+B ; buf1 = tile1 B ; wait all but bB
    STGH(0,     0,     Ag, 0,  0, 512);
    STGH(0,     4096,  Ag, 64, 0, 512);
    STGH(0,     8192,  Bg, 0,  0, 512);
    STGH(0,     12288, Bg, 64, 0, 512);
    STGH(16384, 8192,  Bg, 0,  1, 512);
    STGH(16384, 12288, Bg, 64, 1, 512);
    VMW(4);
    __builtin_amdgcn_sched_barrier(0);
    __builtin_amdgcn_s_barrier();
    __builtin_amdgcn_sched_barrier(0);

    for (int I = 0; I < 3; ++I) {
        const int tb = 2 * I + 1, tc = 2 * I + 2, td = 2 * I + 3;
        PHASE128(0, 0, 1,
                 { STGH(16384, 0, Ag, 0, tb, 512); STGH(16384, 4096, Ag, 64, tb, 512); },
                 (void)0);
        PHASE128(0, 2, 0,
                 { STGH(0, 8192, Bg, 0, tc, 512); STGH(0, 12288, Bg, 64, tc, 512); },
                 VMW(4));
        PHASE128(16384, 0, 1,
                 { STGH(0, 0, Ag, 0, tc, 512); STGH(0, 4096, Ag, 64, tc, 512); },
                 (void)0);
        PHASE128(16384, 2, 0,
                 { STGH(16384, 8192, Bg, 0, td, 512); STGH(16384, 12288, Bg, 64, td, 512); },
                 VMW(4));
    }
    {   // tail: tiles 6 (buf0) / 7 (buf1); only tile7's A left to stage
        PHASE128(0, 0, 1,
                 { STGH(16384, 0, Ag, 0, 7, 512); STGH(16384, 4096, Ag, 64, 7, 512); },
                 (void)0);
        PHASE128(0, 2, 0, (void)0, VMW(0));
        PHASE128(16384, 0, 1, (void)0, (void)0);
        PHASE128(16384, 2, 0, (void)0, (void)0);
    }

    // epilogue: wave w stages its 64x64 to Sh[w*4096], 16B/lane stores
    float bv[4];
#pragma unroll
    for (int j = 0; j < 4; ++j) bv[j] = bias[(int)bn + wn + j * 16 + lr];
    unsigned short* Cs = Sh + w * 4096;
#pragma unroll
    for (int m = 0; m < 4; ++m)
#pragma unroll
        for (int j = 0; j < 4; ++j)
#pragma unroll
            for (int r = 0; r < 4; ++r) {
                float v = acc[m][j][r] + bv[j];
                if (relu) v = fmaxf(v, 0.f);
                Cs[(m * 16 + quad * 4 + r) * 64 + j * 16 + lr] = f2b(v);
            }
    const int rl = lane >> 3, c8 = (lane & 7) * 8;
#pragma unroll
    for (int k = 0; k < 8; ++k) {
        const int row = rl + k * 8;
        ushort8v val = *(const ushort8v*)&Cs[row * 64 + c8];
        *(ushort8v*)(outB + (size_t)(bm + wm + row) * N + bn + wn + c8) = val;
    }
}

// ======= 256x128 4-phase GEMM, runtime N (out stride) and K ==================
// mode 0: outB = A@W^T + bias ; 1: + f32 residual resA/resB (rows <8192 /
// >=8192) ; 2: + b2f(outB) in place.
__global__ __launch_bounds__(512, 2) void gemm_n128(
    const unsigned short* __restrict__ A, const unsigned short* __restrict__ Wt,
    const float* __restrict__ bias,
    const float* __restrict__ resA, const float* __restrict__ resB,
    unsigned short* __restrict__ outB, int N, int K, int mode)
{
    __shared__ __align__(16) unsigned short Sh[49152];   // 96 KiB
    const int tid = threadIdx.x;
    const int lane = tid & 63;
    const int w = tid >> 6;              // 0..7
    const int wm = (w >> 1) * 64;        // 0/64/128/192
    const int wn = (w & 1) * 64;         // 0/64
    const int lr = lane & 15;
    const int quad = lane >> 4;
    const int xo0 = ((quad ^ (lr & 7)) << 3);
    const int xo1 = (((4 | quad) ^ (lr & 7)) << 3);

    // 2D XCD chunking: xcd owns 8 consecutive m-tiles x all n-tiles.
    const int b0 = blockIdx.x;
    const int xcd = b0 & 7, slot = b0 >> 3;
    const size_t bm = (size_t)(xcd * 8 + (slot & 7)) * 256;
    const size_t bn = (size_t)(slot >> 3) * 128;

    const int ar = tid >> 3;
    const int sw = ((tid & 7) ^ (ar & 7)) << 3;
    const unsigned short* Ag = A  + (bm + ar) * (size_t)K + sw;
    const unsigned short* Bg = Wt + (bn + ar) * (size_t)K + sw;
    const int ld = tid * 8;

    frag_cd acc[4][4] = {};
    frag_ab bf[4][2];

    // prologue: aB aA0 aA1 bB ; wait all but bB
    STG(0,     16384, Bg, 0,   0, K);
    STG(0,     0,     Ag, 0,   0, K);
    STG(0,     8192,  Ag, 128, 0, K);
    STG(24576, 16384, Bg, 0,   1, K);
    VMW(2);
    __builtin_amdgcn_sched_barrier(0);
    __builtin_amdgcn_s_barrier();
    __builtin_amdgcn_sched_barrier(0);

    const int nIter = K >> 7;            // 2 K-tiles per iteration
    for (int I = 0; I < nIter - 1; ++I) {
        const int tb = 2 * I + 1, tc = 2 * I + 2, td = 2 * I + 3;
        PHASE(0,     0, 1, { STG(24576, 0, Ag, 0, tb, K); STG(24576, 8192, Ag, 128, tb, K); }, (void)0);
        PHASE(0,     2, 0, STG(0, 16384, Bg, 0, tc, K), VMW(2));
        PHASE(24576, 0, 1, { STG(0, 0, Ag, 0, tc, K); STG(0, 8192, Ag, 128, tc, K); }, (void)0);
        PHASE(24576, 2, 0, STG(24576, 16384, Bg, 0, td, K), VMW(2));
    }
    {   // tail: computes tiles 2(nIter-1), 2nIter-1; only b's A left to stage
        const int tb = (K >> 6) - 1;
        PHASE(0,     0, 1, { STG(24576, 0, Ag, 0, tb, K); STG(24576, 8192, Ag, 128, tb, K); }, (void)0);
        PHASE(0,     2, 0, (void)0, VMW(0));
        PHASE(24576, 0, 1, (void)0, (void)0);
        PHASE(24576, 2, 0, (void)0, (void)0);
    }

    float bv[4];
#pragma unroll
    for (int j = 0; j < 4; ++j) bv[j] = bias[(int)bn + wn + j * 16 + lr];
    unsigned short* Cs = Sh + w * 4096;
#pragma unroll
    for (int m = 0; m < 4; ++m)
#pragma unroll
        for (int j = 0; j < 4; ++j)
#pragma unroll
            for (int r = 0; r < 4; ++r)
                Cs[(m * 16 + quad * 4 + r) * 64 + j * 16 + lr] = f2b(acc[m][j][r] + bv[j]);
    const int rl = lane >> 3, c8 = (lane & 7) * 8;
#pragma unroll
    for (int k = 0; k < 8; ++k) {
        const int row = rl + k * 8;
        const int grow = (int)bm + wm + row;
        const size_t idx = (size_t)grow * N + bn + wn + c8;
        ushort8v val = *(const ushort8v*)&Cs[row * 64 + c8];
        if (mode == 0) {
            *(ushort8v*)(outB + idx) = val;
            continue;
        }
        float vv[8];
#pragma unroll
        for (int t2 = 0; t2 < 8; ++t2) vv[t2] = b2f(val[t2]);
        if (mode == 1) {
            const float* rp = (grow < 8192) ? resA + idx : resB + idx - (size_t)8192 * N;
            float4 ra = *(const float4*)(rp);
            float4 rb = *(const float4*)(rp + 4);
            vv[0] += ra.x; vv[1] += ra.y; vv[2] += ra.z; vv[3] += ra.w;
            vv[4] += rb.x; vv[5] += rb.y; vv[6] += rb.z; vv[7] += rb.w;
        } else {
            ushort8v old = *(const ushort8v*)(outB + idx);
#pragma unroll
            for (int t2 = 0; t2 < 8; ++t2) vv[t2] += b2f(old[t2]);
        }
        ushort8v o;
#pragma unroll
        for (int t2 = 0; t2 < 8; ++t2) o[t2] = f2b(vv[t2]);
        *(ushort8v*)(outB + idx) = o;
    }
}

// -------- merged fp32->bf16 converts + QKV bias concat --------
__global__ __launch_bounds__(256) void convert_all(
    const float* __restrict__ Wq, const float* __restrict__ Wk,
    const float* __restrict__ Wv, const float* __restrict__ Wo,
    const float* __restrict__ W1, const float* __restrict__ W2,
    const float* __restrict__ question, const float* __restrict__ query,
    const float* __restrict__ bqp, const float* __restrict__ bkp,
    const float* __restrict__ bvp,
    unsigned short* __restrict__ Wqkvb, unsigned short* __restrict__ Wob,
    unsigned short* __restrict__ W1b, unsigned short* __restrict__ W2b,
    unsigned short* __restrict__ Xb, float* __restrict__ bqkv)
{
    const int b = blockIdx.x;
    const float* src; unsigned short* dst; size_t off;
    if (b < 256)        { src = Wq; dst = Wqkvb;          off = (size_t)b * 1024; }
    else if (b < 512)   { src = Wk; dst = Wqkvb + 262144; off = (size_t)(b - 256) * 1024; }
    else if (b < 768)   { src = Wv; dst = Wqkvb + 524288; off = (size_t)(b - 512) * 1024; }
    else if (b < 1024)  { src = Wo; dst = Wob;            off = (size_t)(b - 768) * 1024; }
    else if (b < 2048)  { src = W1; dst = W1b;            off = (size_t)(b - 1024) * 1024; }
    else if (b < 3072)  { src = W2; dst = W2b;            off = (size_t)(b - 2048) * 1024; }
    else if (b < 7168)  { src = question; dst = Xb;       off = (size_t)(b - 3072) * 1024; }
    else if (b < 11264) { src = query; dst = Xb + 4194304; off = (size_t)(b - 7168) * 1024; }
    else {
        const int n = (b - 11264) * 256 + threadIdx.x;   // 0..1535
        bqkv[n] = (n < 512) ? bqp[n] : (n < 1024) ? bkp[n - 512] : bvp[n - 1024];
        return;
    }
    const size_t idx = off + threadIdx.x * 4;
    float4 v = *(const float4*)(src + idx);
    ushort4 o;
    o.x = f2b(v.x); o.y = f2b(v.y); o.z = f2b(v.z); o.w = f2b(v.w);
    *(ushort4*)(dst + idx) = o;
}

// ------- Spart[bh][slice] = sum over 256 l-rows of K^T outer V (merged QKV) ----
__global__ __launch_bounds__(256) void s_kernel(
    const unsigned short* __restrict__ QKV, float* __restrict__ Spart)
{
    const int bh = blockIdx.x;           // 0..31
    const int sl = blockIdx.y;           // 0..NSLICE-1
    const int b = bh >> 3, h = bh & 7;
    const int pass = sl >> 3;
    const int l0 = (sl & 7) * 256;
    __shared__ float Ks[64][64];
    __shared__ float Vs[64][64];
    const int tid = threadIdx.x;
    const int tx = tid & 15, ty = tid >> 4;
    const int srow = tid >> 3;
    const int scol = (tid & 7) * 8;
    const size_t rowbase = (size_t)pass * 8192 + (size_t)b * Lq + l0;

    float acc[4][4] = {};

    for (int t0 = 0; t0 < 256; t0 += 64) {
        const unsigned short* kp0 = QKV + (rowbase + t0 + srow) * 1536 + 512 + h * 64 + scol;
        const unsigned short* kp1 = kp0 + (size_t)32 * 1536;
        ushort8v k0 = *(const ushort8v*)kp0;
        ushort8v v0 = *(const ushort8v*)(kp0 + 512);
        ushort8v k1 = *(const ushort8v*)kp1;
        ushort8v v1 = *(const ushort8v*)(kp1 + 512);
        __syncthreads();
#pragma unroll
        for (int e = 0; e < 8; ++e) {
            Ks[srow][scol + e]      = b2f(k0[e]);
            Vs[srow][scol + e]      = b2f(v0[e]);
            Ks[srow + 32][scol + e] = b2f(k1[e]);
            Vs[srow + 32][scol + e] = b2f(v1[e]);
        }
        __syncthreads();
#pragma unroll 4
        for (int rr = 0; rr < 64; ++rr) {
            const float4 kf = *(const float4*)&Ks[rr][ty * 4];
            const float4 vf = *(const float4*)&Vs[rr][tx * 4];
            acc[0][0] = fmaf(kf.x, vf.x, acc[0][0]);
            acc[0][1] = fmaf(kf.x, vf.y, acc[0][1]);
            acc[0][2] = fmaf(kf.x, vf.z, acc[0][2]);
            acc[0][3] = fmaf(kf.x, vf.w, acc[0][3]);
            acc[1][0] = fmaf(kf.y, vf.x, acc[1][0]);
            acc[1][1] = fmaf(kf.y, vf.y, acc[1][1]);
            acc[1][2] = fmaf(kf.y, vf.z, acc[1][2]);
            acc[1][3] = fmaf(kf.y, vf.w, acc[1][3]);
            acc[2][0] = fmaf(kf.z, vf.x, acc[2][0]);
            acc[2][1] = fmaf(kf.z, vf.y, acc[2][1]);
            acc[2][2] = fmaf(kf.z, vf.z, acc[2][2]);
            acc[2][3] = fmaf(kf.z, vf.w, acc[2][3]);
            acc[3][0] = fmaf(kf.w, vf.x, acc[3][0]);
            acc[3][1] = fmaf(kf.w, vf.y, acc[3][1]);
            acc[3][2] = fmaf(kf.w, vf.z, acc[3][2]);
            acc[3][3] = fmaf(kf.w, vf.w, acc[3][3]);
        }
    }

    float* Sp = Spart + ((size_t)bh * NSLICE + sl) * 4096;
#pragma unroll
    for (int i = 0; i < 4; ++i) {
        float4 o = make_float4(acc[i][0], acc[i][1], acc[i][2], acc[i][3]);
        *(float4*)(Sp + (ty * 4 + i) * 64 + tx * 4) = o;
    }
}

// ------- reduce NSLICE partials -> Sbt bf16, B-layout [bh][khalf][n][kj] -------
__global__ __launch_bounds__(256) void sbt_convert(
    const float* __restrict__ Spart, unsigned short* __restrict__ Sbt)
{
    const int bh = blockIdx.x;
    const int uo = blockIdx.y;           // 0..3
    const float* Sp = Spart + (size_t)bh * (NSLICE * 4096);
    unsigned short* Dp = Sbt + (size_t)bh * 4096;
    const int t = threadIdx.x;
#pragma unroll
    for (int u = 0; u < 4; ++u) {
        const int d = (uo * 4 + u) * 256 + t;
        float v = 0.f;
#pragma unroll
        for (int s = 0; s < NSLICE; ++s) v += Sp[(size_t)s * 4096 + d];
        const int row = d >> 6, col = d & 63;
        Dp[(row >> 5) * 2048 + col * 32 + (row & 31)] = f2b(v);
    }
}

// ------- attn = Q @ S_bh via MFMA; block: 128 rows x 64 cols (one head) -------
__global__ __launch_bounds__(256) void attn_mfma(
    const unsigned short* __restrict__ QKV, const unsigned short* __restrict__ Sbt,
    unsigned short* __restrict__ Ob)
{
    __shared__ __align__(16) unsigned short Sh[2 * 128 * 32 + 2 * 64 * 32];
    unsigned short* At = Sh;
    unsigned short* Bt = Sh + 2 * 128 * 32;
    const int h = blockIdx.x;
    const int rbase = blockIdx.y * 128;
    const int b = (rbase >> 11) & 3;
    const int bh = b * 8 + h;
    const int tid = threadIdx.x;
    const int lane = tid & 63;
    const int w = tid >> 6;
    const int lr = lane & 15;
    const int quad = lane >> 4;

    {
        const int rloc = tid >> 2, c8 = (tid & 3) * 8;
#pragma unroll
        for (int it = 0; it < 4; ++it) {
            const int kk = it & 1, rh = it >> 1;
            const unsigned short* g = QKV +
                ((size_t)rbase + rh * 64 + rloc) * 1536 + h * 64 + kk * 32 + c8;
            GLD16(g, At + kk * 4096 + rh * 2048 + w * 512);
        }
        const unsigned short* Sg = Sbt + (size_t)bh * 4096 + tid * 8;
#pragma unroll
        for (int bi = 0; bi < 2; ++bi)
            GLD16(Sg + bi * 2048, Bt + bi * 2048 + w * 512);
    }
    __syncthreads();

    frag_cd acc[2][4] = {};
#pragma unroll
    for (int kk = 0; kk < 2; ++kk) {
        frag_ab a[2], bfr[4];
#pragma unroll
        for (int i = 0; i < 2; ++i)
            a[i] = *(const frag_ab*)&At[kk * 4096 + (w * 32 + i * 16 + lr) * 32 + quad * 8];
#pragma unroll
        for (int j = 0; j < 4; ++j)
            bfr[j] = *(const frag_ab*)&Bt[kk * 2048 + (j * 16 + lr) * 32 + quad * 8];
#pragma unroll
        for (int i = 0; i < 2; ++i)
#pragma unroll
            for (int j = 0; j < 4; ++j)
                acc[i][j] = __builtin_amdgcn_mfma_f32_16x16x32_bf16(a[i], bfr[j], acc[i][j], 0, 0, 0);
    }

    __syncthreads();
    unsigned short* Cs = Sh + w * 2048;
#pragma unroll
    for (int i = 0; i < 2; ++i)
#pragma unroll
        for (int j = 0; j < 4; ++j)
#pragma unroll
            for (int r = 0; r < 4; ++r)
                Cs[(i * 16 + quad * 4 + r) * 64 + j * 16 + lr] = f2b(acc[i][j][r]);
    const int rl = lane >> 3;
    const int c8o = (lane & 7) * 8;
#pragma unroll
    for (int k = 0; k < 4; ++k) {
        const int row = rl + k * 8;
        ushort8v val = *(const ushort8v*)&Cs[row * 64 + c8o];
        *(ushort8v*)(Ob + (size_t)(rbase + w * 32 + row) * 512 + h * 64 + c8o) = val;
    }
}

// ------- LN wave-per-row, ushort8 vectorized ----------
// out==null: bf16 in place ; else: f32 half-columns (merged rows).
__global__ __launch_bounds__(512) void ln_fast(
    unsigned short* __restrict__ Y, const float* __restrict__ g,
    const float* __restrict__ bta, float* __restrict__ out)
{
    const int blk = blockIdx.x;
    const int tid = threadIdx.x;
    const int wv = tid >> 6, lane = tid & 63;
    const int c0 = lane * 8;
    float4 ga = *(const float4*)(g + c0), gb = *(const float4*)(g + c0 + 4);
    float4 ba = *(const float4*)(bta + c0), bb = *(const float4*)(bta + c0 + 4);
    const float gv[8] = {ga.x, ga.y, ga.z, ga.w, gb.x, gb.y, gb.z, gb.w};
    const float bv[8] = {ba.x, ba.y, ba.z, ba.w, bb.x, bb.y, bb.z, bb.w};
#pragma unroll
    for (int r = 0; r < 8; ++r) {
        const int row = blk * 64 + r * 8 + wv;
        unsigned short* yr = Y + (size_t)row * Dq;
        ushort8v v = *(const ushort8v*)(yr + c0);
        float f[8];
        float s = 0.f;
#pragma unroll
        for (int e = 0; e < 8; ++e) { f[e] = b2f(v[e]); s += f[e]; }
#pragma unroll
        for (int off = 32; off; off >>= 1) s += __shfl_xor(s, off, 64);
        const float mean = s * (1.f / Dq);
        float q = 0.f;
#pragma unroll
        for (int e = 0; e < 8; ++e) { f[e] -= mean; q += f[e] * f[e]; }
#pragma unroll
        for (int off = 32; off; off >>= 1) q += __shfl_xor(q, off, 64);
        const float rstd = rsqrtf(q * (1.f / Dq) + 1e-5f);
        if (out) {
            const int half = row >> 13, br = row & 8191;
            float* orow = out + (size_t)br * 1024 + half * 512 + c0;
            float4 o0, o1;
            o0.x = f[0] * rstd * gv[0] + bv[0];
            o0.y = f[1] * rstd * gv[1] + bv[1];
            o0.z = f[2] * rstd * gv[2] + bv[2];
            o0.w = f[3] * rstd * gv[3] + bv[3];
            o1.x = f[4] * rstd * gv[4] + bv[4];
            o1.y = f[5] * rstd * gv[5] + bv[5];
            o1.z = f[6] * rstd * gv[6] + bv[6];
            o1.w = f[7] * rstd * gv[7] + bv[7];
            *(float4*)orow = o0;
            *(float4*)(orow + 4) = o1;
        } else {
            ushort8v o;
#pragma unroll
            for (int e = 0; e < 8; ++e) o[e] = f2b(f[e] * rstd * gv[e] + bv[e]);
            *(ushort8v*)(yr + c0) = o;
        }
    }
}

extern "C" void kernel_launch(void* const* d_in, const int* in_sizes, int n_in,
                              void* d_out, int out_size, void* d_ws, size_t ws_size,
                              hipStream_t stream)
{
    const float* question = (const float*)d_in[0];
    const float* query    = (const float*)d_in[1];
    const float* Wq = (const float*)d_in[2];  const float* bqp = (const float*)d_in[3];
    const float* Wk = (const float*)d_in[4];  const float* bkp = (const float*)d_in[5];
    const float* Wv = (const float*)d_in[6];  const float* bvp = (const float*)d_in[7];
    const float* Wo = (const float*)d_in[8];  const float* bo  = (const float*)d_in[9];
    const float* ln_g = (const float*)d_in[10]; const float* ln_b = (const float*)d_in[11];
    const float* W1 = (const float*)d_in[12]; const float* b1 = (const float*)d_in[13];
    const float* W2 = (const float*)d_in[14]; const float* b2 = (const float*)d_in[15];
    float* out = (float*)d_out;
    char* ws = (char*)d_ws;

    // ---- workspace (~87 MiB), R14 layout ----
    unsigned short* QKVb  = (unsigned short*)(ws);               // [16384][1536] 48 MiB
    unsigned short* attnb = (unsigned short*)(ws + 48 * MiBu);   // 16 MiB
    float* Spart          = (float*)(ws + 48 * MiBu);            // 8 MiB, dead before attnb
    unsigned short* Xb    = (unsigned short*)(ws + 64 * MiBu);   // 16 MiB
    unsigned short* xbuf  = (unsigned short*)(ws + 64 * MiBu);   // y0b -> xb -> y (aliases Xb)
    unsigned short* hb    = (unsigned short*)(ws);               // [16384][2048] 64 MiB
    char* wp = ws + 80 * MiBu + 524288;
    unsigned short* Wqkvb = (unsigned short*)wp;  wp += 1536 * 512 * 2;
    unsigned short* Wob   = (unsigned short*)wp;  wp += 512 * 512 * 2;
    unsigned short* W1b   = (unsigned short*)wp;  wp += 2048 * 512 * 2;
    unsigned short* W2b   = (unsigned short*)wp;  wp += 512 * 2048 * 2;
    unsigned short* Sbt   = (unsigned short*)wp;  wp += 32 * 4096 * 2;
    float* bqkv           = (float*)wp;

    dim3 blk(256);

    convert_all<<<11270, blk, 0, stream>>>(Wq, Wk, Wv, Wo, W1, W2, question, query,
                                           bqp, bkp, bvp,
                                           Wqkvb, Wob, W1b, W2b, Xb, bqkv);

    // QKV: [16384,512]@[1536,512]^T -> bf16 (256x128 4-phase; 768 blocks = 3 rounds)
    gemm_n128<<<dim3(768), dim3(512), 0, stream>>>(Xb, Wqkvb, bqkv,
                                                   nullptr, nullptr, QKVb,
                                                   1536, 512, 0);

    // S partials (fp32, no atomics) -> reduce+pack bf16 B-layout; attn via MFMA
    s_kernel<<<dim3(32, NSLICE), blk, 0, stream>>>(QKVb, Spart);
    sbt_convert<<<dim3(32, 4), blk, 0, stream>>>(Spart, Sbt);
    attn_mfma<<<dim3(8, 128), blk, 0, stream>>>(QKVb, Sbt, attnb);

    // o-proj + residual(inputs f32) + bo -> bf16 y0b (256 blocks)
    gemm_n128<<<dim3(256), dim3(512), 0, stream>>>(attnb, Wob, bo,
                                                   question, query, xbuf,
                                                   512, 512, 1);

    // LN1 in place: xb = LN(y0b)
    ln_fast<<<dim3(256), dim3(512), 0, stream>>>(xbuf, ln_g, ln_b, nullptr);

    // FFN1: h = relu(xb @ W1^T + b1) — 128x128 4-phase, 2 blocks/CU
    // (2048 blocks = 4 balanced rounds at 2/CU)
    gemm_128<<<dim3(2048), dim3(256), 0, stream>>>(xbuf, W1b, b1, hb,
                                                   Mrows, PFq, 1);

    // FFN2, K=2048: y = h @ W2^T + b2 + xb, bf16 in place (256 blocks)
    gemm_n128<<<dim3(256), dim3(512), 0, stream>>>(hb, W2b, b2,
                                                   nullptr, nullptr, xbuf,
                                                   512, 2048, 2);

    // LN2 -> out halves
    ln_fast<<<dim3(256), dim3(512), 0, stream>>>(xbuf, ln_g, ln_b, out);
}

// Round 13
// 287.768 us; speedup vs baseline: 2.2179x; 1.0236x over previous
//
#include <hip/hip_runtime.h>
#include <stdint.h>

// CrossAttention via linear-attention algebra, both halves merged to M=16384:
//   S = K1^T V1 + K2^T V2 (per b,h; 64x64), shared by both halves.
//   attn = Q @ S ; x = LN(inp + attn@Wo^T + bo) ; out = LN(x + FF(x))
// R21: FFN1 on gemm_128 (128x128, 4-phase, 64KiB LDS -> 2 blocks/CU): total
// 304->294.5us. Win came from block-level overlap (m114): with 2 co-resident
// blocks the CU fills barrier drains + kernel-edge tails with the other block.
// R22: extend to the remaining GEMMs — gemm_128n = gemm_128 structure with
// runtime N/K + epilogue modes {0 bias, 1 f32-residual, 2 in-place}; QKV
// (1536 blocks = 3 rounds at 2/CU), o-proj (512 = 1 round), FFN2 (512 = 1
// round) moved onto it. gemm_n128 (96KiB, 1 block/CU) deleted.

#define Bq 4
#define Lq 2048
#define Dq 512
#define PFq 2048
#define Mrows 16384
#define MiBu 1048576ull
#define NSLICE 16

typedef __attribute__((ext_vector_type(8))) short frag_ab;
typedef __attribute__((ext_vector_type(4))) float frag_cd;
typedef __attribute__((ext_vector_type(8))) unsigned short ushort8v;

__device__ __forceinline__ unsigned short f2b(float f) {
    union { float f; uint32_t u; } x; x.f = f;
    uint32_t r = x.u + 0x7fffu + ((x.u >> 16) & 1u);
    return (unsigned short)(r >> 16);
}
__device__ __forceinline__ float b2f(unsigned short u) {
    union { uint32_t u; float f; } x; x.u = ((uint32_t)u) << 16;
    return x.f;
}

#define GLD16(g, l)                                                              \
    __builtin_amdgcn_global_load_lds(                                            \
        (const __attribute__((address_space(1))) void*)(const void*)(g),         \
        (__attribute__((address_space(3))) void*)(void*)(l), 16, 0, 0)

// Stage unit (256-thread kernels): 64 rows x 64 k-cols bf16
#define STGH(BUFOFS, REGOFS, GB, ROWOFS, TILE, KS)                               \
    { GLD16((GB) + (size_t)(ROWOFS) * (KS) + (size_t)(TILE) * 64,                \
            Sh + (BUFOFS) + (REGOFS) + ld);                                      \
      GLD16((GB) + ((size_t)(ROWOFS) + 32) * (KS) + (size_t)(TILE) * 64,         \
            Sh + (BUFOFS) + (REGOFS) + ld + 2048); }

#define VMW(N) asm volatile("s_waitcnt vmcnt(" #N ")" ::: "memory")

// Phase for 128-wide A/B tiles (B region at CB+8192)
#define PHASE128(CB, M0, LOADB, STAGE_STMT, WAIT_STMT)                           \
    {                                                                            \
        frag_ab a00 = *(const frag_ab*)&Sh[(CB) + (wm + (M0)*16 + lr) * 64 + xo0];      \
        frag_ab a01 = *(const frag_ab*)&Sh[(CB) + (wm + (M0)*16 + lr) * 64 + xo1];      \
        frag_ab a10 = *(const frag_ab*)&Sh[(CB) + (wm + (M0)*16 + 16 + lr) * 64 + xo0]; \
        frag_ab a11 = *(const frag_ab*)&Sh[(CB) + (wm + (M0)*16 + 16 + lr) * 64 + xo1]; \
        if (LOADB) {                                                             \
            _Pragma("unroll")                                                    \
            for (int j = 0; j < 4; ++j) {                                        \
                bf[j][0] = *(const frag_ab*)&Sh[(CB) + 8192 + (wn + j*16 + lr)*64 + xo0]; \
                bf[j][1] = *(const frag_ab*)&Sh[(CB) + 8192 + (wn + j*16 + lr)*64 + xo1]; \
            }                                                                    \
        }                                                                        \
        STAGE_STMT;                                                              \
        WAIT_STMT;                                                               \
        __builtin_amdgcn_sched_barrier(0);                                       \
        __builtin_amdgcn_s_barrier();                                            \
        asm volatile("s_waitcnt lgkmcnt(0)" ::: "memory");                       \
        __builtin_amdgcn_sched_barrier(0);                                       \
        __builtin_amdgcn_s_setprio(1);                                           \
        _Pragma("unroll")                                                        \
        for (int j = 0; j < 4; ++j) {                                            \
            acc[(M0)][j]   = __builtin_amdgcn_mfma_f32_16x16x32_bf16(a00, bf[j][0], acc[(M0)][j], 0,0,0);   \
            acc[(M0)][j]   = __builtin_amdgcn_mfma_f32_16x16x32_bf16(a01, bf[j][1], acc[(M0)][j], 0,0,0);   \
            acc[(M0)+1][j] = __builtin_amdgcn_mfma_f32_16x16x32_bf16(a10, bf[j][0], acc[(M0)+1][j], 0,0,0); \
            acc[(M0)+1][j] = __builtin_amdgcn_mfma_f32_16x16x32_bf16(a11, bf[j][1], acc[(M0)+1][j], 0,0,0); \
        }                                                                        \
        __builtin_amdgcn_s_setprio(0);                                           \
        __builtin_amdgcn_sched_barrier(0);                                       \
        __builtin_amdgcn_s_barrier();                                            \
        __builtin_amdgcn_sched_barrier(0);                                       \
    }

// ===== 128x128 4-phase GEMM, 2 blocks/CU (64 KiB LDS), K=512, bias+relu =====
// (R21 kernel, unchanged — measured best for FFN1.)
__global__ __launch_bounds__(256, 2) void gemm_128(
    const unsigned short* __restrict__ A, const unsigned short* __restrict__ Wt,
    const float* __restrict__ bias, unsigned short* __restrict__ outB,
    int M, int N, int relu)
{
    __shared__ __align__(16) unsigned short Sh[32768];   // 64 KiB
    const int tid = threadIdx.x;
    const int lane = tid & 63;
    const int w = tid >> 6;              // 0..3
    const int wm = (w >> 1) * 64;        // 0/64
    const int wn = (w & 1) * 64;         // 0/64
    const int lr = lane & 15;
    const int quad = lane >> 4;
    const int xo0 = ((quad ^ (lr & 7)) << 3);
    const int xo1 = (((4 | quad) ^ (lr & 7)) << 3);

    const int b0 = blockIdx.x;
    const int xcd = b0 & 7, slot = b0 >> 3;
    const int mloc = (M >> 7) >> 3;
    const size_t bm = (size_t)(xcd * mloc + slot % mloc) * 128;
    const size_t bn = (size_t)(slot / mloc) * 128;

    const int ar = tid >> 3;
    const int sw = ((tid & 7) ^ (ar & 7)) << 3;
    const unsigned short* Ag = A  + (bm + ar) * (size_t)512 + sw;
    const unsigned short* Bg = Wt + (bn + ar) * (size_t)512 + sw;
    const int ld = tid * 8;

    frag_cd acc[4][4] = {};
    frag_ab bf[4][2];

    STGH(0,     0,     Ag, 0,  0, 512);
    STGH(0,     4096,  Ag, 64, 0, 512);
    STGH(0,     8192,  Bg, 0,  0, 512);
    STGH(0,     12288, Bg, 64, 0, 512);
    STGH(16384, 8192,  Bg, 0,  1, 512);
    STGH(16384, 12288, Bg, 64, 1, 512);
    VMW(4);
    __builtin_amdgcn_sched_barrier(0);
    __builtin_amdgcn_s_barrier();
    __builtin_amdgcn_sched_barrier(0);

    for (int I = 0; I < 3; ++I) {
        const int tb = 2 * I + 1, tc = 2 * I + 2, td = 2 * I + 3;
        PHASE128(0, 0, 1,
                 { STGH(16384, 0, Ag, 0, tb, 512); STGH(16384, 4096, Ag, 64, tb, 512); },
                 (void)0);
        PHASE128(0, 2, 0,
                 { STGH(0, 8192, Bg, 0, tc, 512); STGH(0, 12288, Bg, 64, tc, 512); },
                 VMW(4));
        PHASE128(16384, 0, 1,
                 { STGH(0, 0, Ag, 0, tc, 512); STGH(0, 4096, Ag, 64, tc, 512); },
                 (void)0);
        PHASE128(16384, 2, 0,
                 { STGH(16384, 8192, Bg, 0, td, 512); STGH(16384, 12288, Bg, 64, td, 512); },
                 VMW(4));
    }
    {
        PHASE128(0, 0, 1,
                 { STGH(16384, 0, Ag, 0, 7, 512); STGH(16384, 4096, Ag, 64, 7, 512); },
                 (void)0);
        PHASE128(0, 2, 0, (void)0, VMW(0));
        PHASE128(16384, 0, 1, (void)0, (void)0);
        PHASE128(16384, 2, 0, (void)0, (void)0);
    }

    float bv[4];
#pragma unroll
    for (int j = 0; j < 4; ++j) bv[j] = bias[(int)bn + wn + j * 16 + lr];
    unsigned short* Cs = Sh + w * 4096;
#pragma unroll
    for (int m = 0; m < 4; ++m)
#pragma unroll
        for (int j = 0; j < 4; ++j)
#pragma unroll
            for (int r = 0; r < 4; ++r) {
                float v = acc[m][j][r] + bv[j];
                if (relu) v = fmaxf(v, 0.f);
                Cs[(m * 16 + quad * 4 + r) * 64 + j * 16 + lr] = f2b(v);
            }
    const int rl = lane >> 3, c8 = (lane & 7) * 8;
#pragma unroll
    for (int k = 0; k < 8; ++k) {
        const int row = rl + k * 8;
        ushort8v val = *(const ushort8v*)&Cs[row * 64 + c8];
        *(ushort8v*)(outB + (size_t)(bm + wm + row) * N + bn + wn + c8) = val;
    }
}

// ====== 128x128 4-phase GEMM, 2 blocks/CU, runtime N/K + epilogue modes =====
// mode 0: outB = A@W^T + bias ; 1: + f32 residual resA/resB (rows <8192 /
// >=8192) ; 2: + b2f(outB) in place. grid (M/128)*(N/128), %8==0.
__global__ __launch_bounds__(256, 2) void gemm_128n(
    const unsigned short* __restrict__ A, const unsigned short* __restrict__ Wt,
    const float* __restrict__ bias,
    const float* __restrict__ resA, const float* __restrict__ resB,
    unsigned short* __restrict__ outB, int M, int N, int K, int mode)
{
    __shared__ __align__(16) unsigned short Sh[32768];   // 64 KiB
    const int tid = threadIdx.x;
    const int lane = tid & 63;
    const int w = tid >> 6;              // 0..3
    const int wm = (w >> 1) * 64;
    const int wn = (w & 1) * 64;
    const int lr = lane & 15;
    const int quad = lane >> 4;
    const int xo0 = ((quad ^ (lr & 7)) << 3);
    const int xo1 = (((4 | quad) ^ (lr & 7)) << 3);

    const int b0 = blockIdx.x;
    const int xcd = b0 & 7, slot = b0 >> 3;
    const int mloc = (M >> 7) >> 3;
    const size_t bm = (size_t)(xcd * mloc + slot % mloc) * 128;
    const size_t bn = (size_t)(slot / mloc) * 128;

    const int ar = tid >> 3;
    const int sw = ((tid & 7) ^ (ar & 7)) << 3;
    const unsigned short* Ag = A  + (bm + ar) * (size_t)K + sw;
    const unsigned short* Bg = Wt + (bn + ar) * (size_t)K + sw;
    const int ld = tid * 8;

    frag_cd acc[4][4] = {};
    frag_ab bf[4][2];

    // prologue: buf0 = tile0 A+B ; buf1 = tile1 B ; wait all but bB
    STGH(0,     0,     Ag, 0,  0, K);
    STGH(0,     4096,  Ag, 64, 0, K);
    STGH(0,     8192,  Bg, 0,  0, K);
    STGH(0,     12288, Bg, 64, 0, K);
    STGH(16384, 8192,  Bg, 0,  1, K);
    STGH(16384, 12288, Bg, 64, 1, K);
    VMW(4);
    __builtin_amdgcn_sched_barrier(0);
    __builtin_amdgcn_s_barrier();
    __builtin_amdgcn_sched_barrier(0);

    const int nIter = K >> 7;            // 2 K-tiles per iteration
    for (int I = 0; I < nIter - 1; ++I) {
        const int tb = 2 * I + 1, tc = 2 * I + 2, td = 2 * I + 3;
        PHASE128(0, 0, 1,
                 { STGH(16384, 0, Ag, 0, tb, K); STGH(16384, 4096, Ag, 64, tb, K); },
                 (void)0);
        PHASE128(0, 2, 0,
                 { STGH(0, 8192, Bg, 0, tc, K); STGH(0, 12288, Bg, 64, tc, K); },
                 VMW(4));
        PHASE128(16384, 0, 1,
                 { STGH(0, 0, Ag, 0, tc, K); STGH(0, 4096, Ag, 64, tc, K); },
                 (void)0);
        PHASE128(16384, 2, 0,
                 { STGH(16384, 8192, Bg, 0, td, K); STGH(16384, 12288, Bg, 64, td, K); },
                 VMW(4));
    }
    {   // tail: last tile's A into buf1; drain once
        const int tb = (K >> 6) - 1;
        PHASE128(0, 0, 1,
                 { STGH(16384, 0, Ag, 0, tb, K); STGH(16384, 4096, Ag, 64, tb, K); },
                 (void)0);
        PHASE128(0, 2, 0, (void)0, VMW(0));
        PHASE128(16384, 0, 1, (void)0, (void)0);
        PHASE128(16384, 2, 0, (void)0, (void)0);
    }

    // epilogue: wave w stages its 64x64 to Sh[w*4096]; residual post-LDS
    float bv[4];
#pragma unroll
    for (int j = 0; j < 4; ++j) bv[j] = bias[(int)bn + wn + j * 16 + lr];
    unsigned short* Cs = Sh + w * 4096;
#pragma unroll
    for (int m = 0; m < 4; ++m)
#pragma unroll
        for (int j = 0; j < 4; ++j)
#pragma unroll
            for (int r = 0; r < 4; ++r)
                Cs[(m * 16 + quad * 4 + r) * 64 + j * 16 + lr] = f2b(acc[m][j][r] + bv[j]);
    const int rl = lane >> 3, c8 = (lane & 7) * 8;
#pragma unroll
    for (int k = 0; k < 8; ++k) {
        const int row = rl + k * 8;
        const int grow = (int)bm + wm + row;
        const size_t idx = (size_t)grow * N + bn + wn + c8;
        ushort8v val = *(const ushort8v*)&Cs[row * 64 + c8];
        if (mode == 0) {
            *(ushort8v*)(outB + idx) = val;
            continue;
        }
        float vv[8];
#pragma unroll
        for (int t2 = 0; t2 < 8; ++t2) vv[t2] = b2f(val[t2]);
        if (mode == 1) {
            const float* rp = (grow < 8192) ? resA + idx : resB + idx - (size_t)8192 * N;
            float4 ra = *(const float4*)(rp);
            float4 rb = *(const float4*)(rp + 4);
            vv[0] += ra.x; vv[1] += ra.y; vv[2] += ra.z; vv[3] += ra.w;
            vv[4] += rb.x; vv[5] += rb.y; vv[6] += rb.z; vv[7] += rb.w;
        } else {
            ushort8v old = *(const ushort8v*)(outB + idx);
#pragma unroll
            for (int t2 = 0; t2 < 8; ++t2) vv[t2] += b2f(old[t2]);
        }
        ushort8v o;
#pragma unroll
        for (int t2 = 0; t2 < 8; ++t2) o[t2] = f2b(vv[t2]);
        *(ushort8v*)(outB + idx) = o;
    }
}

// -------- merged fp32->bf16 converts + QKV bias concat --------
__global__ __launch_bounds__(256) void convert_all(
    const float* __restrict__ Wq, const float* __restrict__ Wk,
    const float* __restrict__ Wv, const float* __restrict__ Wo,
    const float* __restrict__ W1, const float* __restrict__ W2,
    const float* __restrict__ question, const float* __restrict__ query,
    const float* __restrict__ bqp, const float* __restrict__ bkp,
    const float* __restrict__ bvp,
    unsigned short* __restrict__ Wqkvb, unsigned short* __restrict__ Wob,
    unsigned short* __restrict__ W1b, unsigned short* __restrict__ W2b,
    unsigned short* __restrict__ Xb, float* __restrict__ bqkv)
{
    const int b = blockIdx.x;
    const float* src; unsigned short* dst; size_t off;
    if (b < 256)        { src = Wq; dst = Wqkvb;          off = (size_t)b * 1024; }
    else if (b < 512)   { src = Wk; dst = Wqkvb + 262144; off = (size_t)(b - 256) * 1024; }
    else if (b < 768)   { src = Wv; dst = Wqkvb + 524288; off = (size_t)(b - 512) * 1024; }
    else if (b < 1024)  { src = Wo; dst = Wob;            off = (size_t)(b - 768) * 1024; }
    else if (b < 2048)  { src = W1; dst = W1b;            off = (size_t)(b - 1024) * 1024; }
    else if (b < 3072)  { src = W2; dst = W2b;            off = (size_t)(b - 2048) * 1024; }
    else if (b < 7168)  { src = question; dst = Xb;       off = (size_t)(b - 3072) * 1024; }
    else if (b < 11264) { src = query; dst = Xb + 4194304; off = (size_t)(b - 7168) * 1024; }
    else {
        const int n = (b - 11264) * 256 + threadIdx.x;   // 0..1535
        bqkv[n] = (n < 512) ? bqp[n] : (n < 1024) ? bkp[n - 512] : bvp[n - 1024];
        return;
    }
    const size_t idx = off + threadIdx.x * 4;
    float4 v = *(const float4*)(src + idx);
    ushort4 o;
    o.x = f2b(v.x); o.y = f2b(v.y); o.z = f2b(v.z); o.w = f2b(v.w);
    *(ushort4*)(dst + idx) = o;
}

// ------- Spart[bh][slice] = sum over 256 l-rows of K^T outer V (merged QKV) ----
__global__ __launch_bounds__(256) void s_kernel(
    const unsigned short* __restrict__ QKV, float* __restrict__ Spart)
{
    const int bh = blockIdx.x;           // 0..31
    const int sl = blockIdx.y;           // 0..NSLICE-1
    const int b = bh >> 3, h = bh & 7;
    const int pass = sl >> 3;
    const int l0 = (sl & 7) * 256;
    __shared__ float Ks[64][64];
    __shared__ float Vs[64][64];
    const int tid = threadIdx.x;
    const int tx = tid & 15, ty = tid >> 4;
    const int srow = tid >> 3;
    const int scol = (tid & 7) * 8;
    const size_t rowbase = (size_t)pass * 8192 + (size_t)b * Lq + l0;

    float acc[4][4] = {};

    for (int t0 = 0; t0 < 256; t0 += 64) {
        const unsigned short* kp0 = QKV + (rowbase + t0 + srow) * 1536 + 512 + h * 64 + scol;
        const unsigned short* kp1 = kp0 + (size_t)32 * 1536;
        ushort8v k0 = *(const ushort8v*)kp0;
        ushort8v v0 = *(const ushort8v*)(kp0 + 512);
        ushort8v k1 = *(const ushort8v*)kp1;
        ushort8v v1 = *(const ushort8v*)(kp1 + 512);
        __syncthreads();
#pragma unroll
        for (int e = 0; e < 8; ++e) {
            Ks[srow][scol + e]      = b2f(k0[e]);
            Vs[srow][scol + e]      = b2f(v0[e]);
            Ks[srow + 32][scol + e] = b2f(k1[e]);
            Vs[srow + 32][scol + e] = b2f(v1[e]);
        }
        __syncthreads();
#pragma unroll 4
        for (int rr = 0; rr < 64; ++rr) {
            const float4 kf = *(const float4*)&Ks[rr][ty * 4];
            const float4 vf = *(const float4*)&Vs[rr][tx * 4];
            acc[0][0] = fmaf(kf.x, vf.x, acc[0][0]);
            acc[0][1] = fmaf(kf.x, vf.y, acc[0][1]);
            acc[0][2] = fmaf(kf.x, vf.z, acc[0][2]);
            acc[0][3] = fmaf(kf.x, vf.w, acc[0][3]);
            acc[1][0] = fmaf(kf.y, vf.x, acc[1][0]);
            acc[1][1] = fmaf(kf.y, vf.y, acc[1][1]);
            acc[1][2] = fmaf(kf.y, vf.z, acc[1][2]);
            acc[1][3] = fmaf(kf.y, vf.w, acc[1][3]);
            acc[2][0] = fmaf(kf.z, vf.x, acc[2][0]);
            acc[2][1] = fmaf(kf.z, vf.y, acc[2][1]);
            acc[2][2] = fmaf(kf.z, vf.z, acc[2][2]);
            acc[2][3] = fmaf(kf.z, vf.w, acc[2][3]);
            acc[3][0] = fmaf(kf.w, vf.x, acc[3][0]);
            acc[3][1] = fmaf(kf.w, vf.y, acc[3][1]);
            acc[3][2] = fmaf(kf.w, vf.z, acc[3][2]);
            acc[3][3] = fmaf(kf.w, vf.w, acc[3][3]);
        }
    }

    float* Sp = Spart + ((size_t)bh * NSLICE + sl) * 4096;
#pragma unroll
    for (int i = 0; i < 4; ++i) {
        float4 o = make_float4(acc[i][0], acc[i][1], acc[i][2], acc[i][3]);
        *(float4*)(Sp + (ty * 4 + i) * 64 + tx * 4) = o;
    }
}

// ------- reduce NSLICE partials -> Sbt bf16, B-layout [bh][khalf][n][kj] -------
__global__ __launch_bounds__(256) void sbt_convert(
    const float* __restrict__ Spart, unsigned short* __restrict__ Sbt)
{
    const int bh = blockIdx.x;
    const int uo = blockIdx.y;           // 0..3
    const float* Sp = Spart + (size_t)bh * (NSLICE * 4096);
    unsigned short* Dp = Sbt + (size_t)bh * 4096;
    const int t = threadIdx.x;
#pragma unroll
    for (int u = 0; u < 4; ++u) {
        const int d = (uo * 4 + u) * 256 + t;
        float v = 0.f;
#pragma unroll
        for (int s = 0; s < NSLICE; ++s) v += Sp[(size_t)s * 4096 + d];
        const int row = d >> 6, col = d & 63;
        Dp[(row >> 5) * 2048 + col * 32 + (row & 31)] = f2b(v);
    }
}

// ------- attn = Q @ S_bh via MFMA; block: 128 rows x 64 cols (one head) -------
__global__ __launch_bounds__(256) void attn_mfma(
    const unsigned short* __restrict__ QKV, const unsigned short* __restrict__ Sbt,
    unsigned short* __restrict__ Ob)
{
    __shared__ __align__(16) unsigned short Sh[2 * 128 * 32 + 2 * 64 * 32];
    unsigned short* At = Sh;
    unsigned short* Bt = Sh + 2 * 128 * 32;
    const int h = blockIdx.x;
    const int rbase = blockIdx.y * 128;
    const int b = (rbase >> 11) & 3;
    const int bh = b * 8 + h;
    const int tid = threadIdx.x;
    const int lane = tid & 63;
    const int w = tid >> 6;
    const int lr = lane & 15;
    const int quad = lane >> 4;

    {
        const int rloc = tid >> 2, c8 = (tid & 3) * 8;
#pragma unroll
        for (int it = 0; it < 4; ++it) {
            const int kk = it & 1, rh = it >> 1;
            const unsigned short* g = QKV +
                ((size_t)rbase + rh * 64 + rloc) * 1536 + h * 64 + kk * 32 + c8;
            GLD16(g, At + kk * 4096 + rh * 2048 + w * 512);
        }
        const unsigned short* Sg = Sbt + (size_t)bh * 4096 + tid * 8;
#pragma unroll
        for (int bi = 0; bi < 2; ++bi)
            GLD16(Sg + bi * 2048, Bt + bi * 2048 + w * 512);
    }
    __syncthreads();

    frag_cd acc[2][4] = {};
#pragma unroll
    for (int kk = 0; kk < 2; ++kk) {
        frag_ab a[2], bfr[4];
#pragma unroll
        for (int i = 0; i < 2; ++i)
            a[i] = *(const frag_ab*)&At[kk * 4096 + (w * 32 + i * 16 + lr) * 32 + quad * 8];
#pragma unroll
        for (int j = 0; j < 4; ++j)
            bfr[j] = *(const frag_ab*)&Bt[kk * 2048 + (j * 16 + lr) * 32 + quad * 8];
#pragma unroll
        for (int i = 0; i < 2; ++i)
#pragma unroll
            for (int j = 0; j < 4; ++j)
                acc[i][j] = __builtin_amdgcn_mfma_f32_16x16x32_bf16(a[i], bfr[j], acc[i][j], 0, 0, 0);
    }

    __syncthreads();
    unsigned short* Cs = Sh + w * 2048;
#pragma unroll
    for (int i = 0; i < 2; ++i)
#pragma unroll
        for (int j = 0; j < 4; ++j)
#pragma unroll
            for (int r = 0; r < 4; ++r)
                Cs[(i * 16 + quad * 4 + r) * 64 + j * 16 + lr] = f2b(acc[i][j][r]);
    const int rl = lane >> 3;
    const int c8o = (lane & 7) * 8;
#pragma unroll
    for (int k = 0; k < 4; ++k) {
        const int row = rl + k * 8;
        ushort8v val = *(const ushort8v*)&Cs[row * 64 + c8o];
        *(ushort8v*)(Ob + (size_t)(rbase + w * 32 + row) * 512 + h * 64 + c8o) = val;
    }
}

// ------- LN wave-per-row, ushort8 vectorized ----------
// out==null: bf16 in place ; else: f32 half-columns (merged rows).
__global__ __launch_bounds__(512) void ln_fast(
    unsigned short* __restrict__ Y, const float* __restrict__ g,
    const float* __restrict__ bta, float* __restrict__ out)
{
    const int blk = blockIdx.x;
    const int tid = threadIdx.x;
    const int wv = tid >> 6, lane = tid & 63;
    const int c0 = lane * 8;
    float4 ga = *(const float4*)(g + c0), gb = *(const float4*)(g + c0 + 4);
    float4 ba = *(const float4*)(bta + c0), bb = *(const float4*)(bta + c0 + 4);
    const float gv[8] = {ga.x, ga.y, ga.z, ga.w, gb.x, gb.y, gb.z, gb.w};
    const float bv[8] = {ba.x, ba.y, ba.z, ba.w, bb.x, bb.y, bb.z, bb.w};
#pragma unroll
    for (int r = 0; r < 8; ++r) {
        const int row = blk * 64 + r * 8 + wv;
        unsigned short* yr = Y + (size_t)row * Dq;
        ushort8v v = *(const ushort8v*)(yr + c0);
        float f[8];
        float s = 0.f;
#pragma unroll
        for (int e = 0; e < 8; ++e) { f[e] = b2f(v[e]); s += f[e]; }
#pragma unroll
        for (int off = 32; off; off >>= 1) s += __shfl_xor(s, off, 64);
        const float mean = s * (1.f / Dq);
        float q = 0.f;
#pragma unroll
        for (int e = 0; e < 8; ++e) { f[e] -= mean; q += f[e] * f[e]; }
#pragma unroll
        for (int off = 32; off; off >>= 1) q += __shfl_xor(q, off, 64);
        const float rstd = rsqrtf(q * (1.f / Dq) + 1e-5f);
        if (out) {
            const int half = row >> 13, br = row & 8191;
            float* orow = out + (size_t)br * 1024 + half * 512 + c0;
            float4 o0, o1;
            o0.x = f[0] * rstd * gv[0] + bv[0];
            o0.y = f[1] * rstd * gv[1] + bv[1];
            o0.z = f[2] * rstd * gv[2] + bv[2];
            o0.w = f[3] * rstd * gv[3] + bv[3];
            o1.x = f[4] * rstd * gv[4] + bv[4];
            o1.y = f[5] * rstd * gv[5] + bv[5];
            o1.z = f[6] * rstd * gv[6] + bv[6];
            o1.w = f[7] * rstd * gv[7] + bv[7];
            *(float4*)orow = o0;
            *(float4*)(orow + 4) = o1;
        } else {
            ushort8v o;
#pragma unroll
            for (int e = 0; e < 8; ++e) o[e] = f2b(f[e] * rstd * gv[e] + bv[e]);
            *(ushort8v*)(yr + c0) = o;
        }
    }
}

extern "C" void kernel_launch(void* const* d_in, const int* in_sizes, int n_in,
                              void* d_out, int out_size, void* d_ws, size_t ws_size,
                              hipStream_t stream)
{
    const float* question = (const float*)d_in[0];
    const float* query    = (const float*)d_in[1];
    const float* Wq = (const float*)d_in[2];  const float* bqp = (const float*)d_in[3];
    const float* Wk = (const float*)d_in[4];  const float* bkp = (const float*)d_in[5];
    const float* Wv = (const float*)d_in[6];  const float* bvp = (const float*)d_in[7];
    const float* Wo = (const float*)d_in[8];  const float* bo  = (const float*)d_in[9];
    const float* ln_g = (const float*)d_in[10]; const float* ln_b = (const float*)d_in[11];
    const float* W1 = (const float*)d_in[12]; const float* b1 = (const float*)d_in[13];
    const float* W2 = (const float*)d_in[14]; const float* b2 = (const float*)d_in[15];
    float* out = (float*)d_out;
    char* ws = (char*)d_ws;

    // ---- workspace (~87 MiB), R14 layout ----
    unsigned short* QKVb  = (unsigned short*)(ws);               // [16384][1536] 48 MiB
    unsigned short* attnb = (unsigned short*)(ws + 48 * MiBu);   // 16 MiB
    float* Spart          = (float*)(ws + 48 * MiBu);            // 8 MiB, dead before attnb
    unsigned short* Xb    = (unsigned short*)(ws + 64 * MiBu);   // 16 MiB
    unsigned short* xbuf  = (unsigned short*)(ws + 64 * MiBu);   // y0b -> xb -> y (aliases Xb)
    unsigned short* hb    = (unsigned short*)(ws);               // [16384][2048] 64 MiB
    char* wp = ws + 80 * MiBu + 524288;
    unsigned short* Wqkvb = (unsigned short*)wp;  wp += 1536 * 512 * 2;
    unsigned short* Wob   = (unsigned short*)wp;  wp += 512 * 512 * 2;
    unsigned short* W1b   = (unsigned short*)wp;  wp += 2048 * 512 * 2;
    unsigned short* W2b   = (unsigned short*)wp;  wp += 512 * 2048 * 2;
    unsigned short* Sbt   = (unsigned short*)wp;  wp += 32 * 4096 * 2;
    float* bqkv           = (float*)wp;

    dim3 blk(256);

    convert_all<<<11270, blk, 0, stream>>>(Wq, Wk, Wv, Wo, W1, W2, question, query,
                                           bqp, bkp, bvp,
                                           Wqkvb, Wob, W1b, W2b, Xb, bqkv);

    // QKV: [16384,512]@[1536,512]^T -> bf16 (128-tile, 2 blocks/CU;
    // 1536 blocks = 3 balanced rounds at 2/CU)
    gemm_128n<<<dim3(1536), dim3(256), 0, stream>>>(Xb, Wqkvb, bqkv,
                                                    nullptr, nullptr, QKVb,
                                                    Mrows, 1536, 512, 0);

    // S partials (fp32, no atomics) -> reduce+pack bf16 B-layout; attn via MFMA
    s_kernel<<<dim3(32, NSLICE), blk, 0, stream>>>(QKVb, Spart);
    sbt_convert<<<dim3(32, 4), blk, 0, stream>>>(Spart, Sbt);
    attn_mfma<<<dim3(8, 128), blk, 0, stream>>>(QKVb, Sbt, attnb);

    // o-proj + residual(inputs f32) + bo -> bf16 y0b (512 blocks = 1 round at 2/CU)
    gemm_128n<<<dim3(512), dim3(256), 0, stream>>>(attnb, Wob, bo,
                                                   question, query, xbuf,
                                                   Mrows, 512, 512, 1);

    // LN1 in place: xb = LN(y0b)
    ln_fast<<<dim3(256), dim3(512), 0, stream>>>(xbuf, ln_g, ln_b, nullptr);

    // FFN1: h = relu(xb @ W1^T + b1) — measured-best R21 kernel, unchanged
    gemm_128<<<dim3(2048), dim3(256), 0, stream>>>(xbuf, W1b, b1, hb,
                                                   Mrows, PFq, 1);

    // FFN2, K=2048: y = h @ W2^T + b2 + xb, bf16 in place (512 blocks = 1 round)
    gemm_128n<<<dim3(512), dim3(256), 0, stream>>>(hb, W2b, b2,
                                                   nullptr, nullptr, xbuf,
                                                   Mrows, 512, 2048, 2);

    // LN2 -> out halves
    ln_fast<<<dim3(256), dim3(512), 0, stream>>>(xbuf, ln_g, ln_b, out);
}